// Round 6
// baseline (355.983 us; speedup 1.0000x reference)
//
#include <hip/hip_runtime.h>
#include <hip/hip_bf16.h>

// B=8, C=512, N=2048, P=256.
// Round 16: halve S-phase LDS reads in fused_attn (measured LDS-BW-bound:
// 4 waves each read the FULL 128-key phi hi/lo = 4x multicast waste).
//   - wave = (q-half w&1: 32 rows) x (key-half w>>1: 64 keys). Per chunk:
//     phi reads 16 -> 8 b128, MFMA count unchanged (24) -> 2x fewer
//     S reads/FLOP.
//   - theta-HI for 32q hoisted in regs (64 VGPR, same budget as old hi+lo
//     for 16q); theta-LO streamed per-chunk from global (L2-resident,
//     prefetched 1 chunk ahead).
//   - softmax two-stage: per-wave partial (m,l) over 64 keys -> Msh/Lsh LDS
//     exchange (one extra barrier/tile) -> shared final m, l. P layout, PV
//     square tiling, staging, swizzle unchanged.
// Predicted: fused 100 -> ~80us; MfmaUtil 28 -> ~37; conflicts ~4-5e6;
// VGPR ~144-176; total 267 -> ~245us.

typedef __attribute__((ext_vector_type(8))) short short8;
typedef __attribute__((ext_vector_type(4))) float floatx4;

// ---------------- bf16 helpers ----------------
__device__ __forceinline__ unsigned short f2bf(float v) {
    __hip_bfloat16 h = __float2bfloat16(v);
    return *(unsigned short*)&h;
}
__device__ __forceinline__ float bf2f(unsigned short u) {
    __hip_bfloat16 h;
    *(unsigned short*)&h = u;
    return __bfloat162float(h);
}

// async global->LDS 16B per lane (dest must be wave-linear: base + lane*16)
__device__ __forceinline__ void gl16(const unsigned short* g, unsigned short* l) {
    __builtin_amdgcn_global_load_lds(
        (const __attribute__((address_space(1))) unsigned int*)g,
        (__attribute__((address_space(3))) unsigned int*)l, 16, 0, 0);
}

// transpose + hi/lo split: X [R][N] fp32 -> Thi/Tlo [N][R] bf16 (batched over z)
__global__ __launch_bounds__(256) void transpose_split(
    const float* __restrict__ X, unsigned short* __restrict__ Thi,
    unsigned short* __restrict__ Tlo, int R, int N)
{
    X   += (long)blockIdx.z * R * N;
    Thi += (long)blockIdx.z * N * R;
    Tlo += (long)blockIdx.z * N * R;
    __shared__ float s[32][33];
    const int tx = threadIdx.x & 31, ty = threadIdx.x >> 5;
    const int n0 = blockIdx.x * 32, r0 = blockIdx.y * 32;
#pragma unroll
    for (int r = 0; r < 4; ++r)
        s[ty + r * 8][tx] = X[(long)(r0 + ty + r * 8) * N + n0 + tx];
    __syncthreads();
#pragma unroll
    for (int r = 0; r < 4; ++r) {
        const int n = ty + r * 8;
        const float v = s[tx][n];
        const unsigned short hi = f2bf(v);
        const unsigned short lo = f2bf(v - bf2f(hi));
        Thi[(long)(n0 + n) * R + r0 + tx] = hi;
        Tlo[(long)(n0 + n) * R + r0 + tx] = lo;
    }
}

// concat [Wth; Wph] rows and hi/lo split: out [2P][C]
__global__ __launch_bounds__(256) void split_w2(
    const float* __restrict__ Wth, const float* __restrict__ Wph,
    unsigned short* __restrict__ Whi, unsigned short* __restrict__ Wlo, int PC)
{
    const int i = blockIdx.x * 256 + threadIdx.x;
    if (i < 2 * PC) {
        const float v = (i < PC) ? Wth[i] : Wph[i - PC];
        const unsigned short hi = f2bf(v);
        Whi[i] = hi;
        Wlo[i] = f2bf(v - bf2f(hi));
    }
}

__global__ __launch_bounds__(256) void cast_bf16(
    const float* __restrict__ X, unsigned short* __restrict__ Y)
{
    const long i = ((long)blockIdx.x * 256 + threadIdx.x) * 4;
    const float4 v = *(const float4*)&X[i];
    ushort4 o;
    o.x = f2bf(v.x); o.y = f2bf(v.y); o.z = f2bf(v.z); o.w = f2bf(v.w);
    *(ushort4*)&Y[i] = o;
}

// ---------------- MFMA GEMM (async global_load_lds, double-buffered) ----------
// C[M][N] = A[M][K] * B[N][K]^T, bf16 K-contiguous inputs, fp32 accum.
// OUTMODE: 0 fp32, 1 bf16, 2 hi/lo split bf16, 3 bf16 + BN partials scratch
//          (slot = (bz*gridDim.x+bx)*2 + (wn>>6); [C][256] scratch).
#define BK 32

template <bool SPLIT, int OUTMODE, int FM, int FN>
__global__ __launch_bounds__(256) void mfma_gemm(
    const unsigned short* __restrict__ Ahi, const unsigned short* __restrict__ Alo,
    const unsigned short* __restrict__ Bhi, const unsigned short* __restrict__ Blo,
    void* __restrict__ Cout, void* __restrict__ Cout2,
    int K, int lda, int ldb, int ldc,
    long sA, long sB, long sC,
    float* __restrict__ S1, float* __restrict__ S2)
{
    constexpr int MTM = FM * 32, MTN = FN * 32;
    constexpr int SA = FM / 2, SB = FN / 2;
    constexpr int ASZ = MTM * BK, BSZ = MTN * BK;

    Ahi += (long)blockIdx.z * sA;
    Bhi += (long)blockIdx.z * sB;
    if (SPLIT) { Alo += (long)blockIdx.z * sA; Blo += (long)blockIdx.z * sB; }
    float* Cf = (float*)Cout + (long)blockIdx.z * sC;
    unsigned short* Ch = (unsigned short*)Cout + (long)blockIdx.z * sC;
    unsigned short* Cl = (unsigned short*)Cout2 + (long)blockIdx.z * sC;

    __shared__ unsigned short AsH[2 * ASZ], BsH[2 * BSZ];
    __shared__ unsigned short AsL[SPLIT ? 2 * ASZ : 8], BsL[SPLIT ? 2 * BSZ : 8];

    const int tid = threadIdx.x;
    const int wid = tid >> 6, lane = tid & 63;
    const int wm = (wid >> 1) * (FM * 16), wn = (wid & 1) * (FN * 16);
    const int l15 = lane & 15, quad = lane >> 4;
    const int m0 = blockIdx.y * MTM, n0 = blockIdx.x * MTN;

    int arow[SA], acol[SA], brow[SB], bcol[SB];
#pragma unroll
    for (int t = 0; t < SA; ++t) {
        const int gid = t * 256 + tid;
        arow[t] = gid >> 2; acol[t] = (gid & 3) * 8;
    }
#pragma unroll
    for (int t = 0; t < SB; ++t) {
        const int gid = t * 256 + tid;
        brow[t] = gid >> 2; bcol[t] = (gid & 3) * 8;
    }

    auto stage = [&](int k0, int buf) {
#pragma unroll
        for (int t = 0; t < SA; ++t) {
            const long o = (long)(m0 + arow[t]) * lda + k0 + acol[t];
            const int d = buf * ASZ + (t * 256 + tid) * 8;
            gl16(&Ahi[o], &AsH[d]);
            if (SPLIT) gl16(&Alo[o], &AsL[d]);
        }
#pragma unroll
        for (int t = 0; t < SB; ++t) {
            const long o = (long)(n0 + brow[t]) * ldb + k0 + bcol[t];
            const int d = buf * BSZ + (t * 256 + tid) * 8;
            gl16(&Bhi[o], &BsH[d]);
            if (SPLIT) gl16(&Blo[o], &BsL[d]);
        }
    };

    floatx4 acc[FM][FN];
#pragma unroll
    for (int i = 0; i < FM; ++i)
#pragma unroll
        for (int j = 0; j < FN; ++j) acc[i][j] = (floatx4){0.f, 0.f, 0.f, 0.f};

    const int iters = K / BK;
    stage(0, 0);
    __syncthreads();

    for (int it = 0; it < iters; ++it) {
        const int cur = it & 1;
        if (it + 1 < iters) stage((it + 1) * BK, cur ^ 1);

        short8 ah[FM], bh[FN], al[SPLIT ? FM : 1], bl[SPLIT ? FN : 1];
#pragma unroll
        for (int i = 0; i < FM; ++i) {
            ah[i] = *(const short8*)&AsH[cur * ASZ + (wm + i * 16 + l15) * BK + quad * 8];
            if (SPLIT) al[i] = *(const short8*)&AsL[cur * ASZ + (wm + i * 16 + l15) * BK + quad * 8];
        }
#pragma unroll
        for (int j = 0; j < FN; ++j) {
            bh[j] = *(const short8*)&BsH[cur * BSZ + (wn + j * 16 + l15) * BK + quad * 8];
            if (SPLIT) bl[j] = *(const short8*)&BsL[cur * BSZ + (wn + j * 16 + l15) * BK + quad * 8];
        }
#pragma unroll
        for (int i = 0; i < FM; ++i)
#pragma unroll
            for (int j = 0; j < FN; ++j) {
                acc[i][j] = __builtin_amdgcn_mfma_f32_16x16x32_bf16(ah[i], bh[j], acc[i][j], 0, 0, 0);
                if (SPLIT) {
                    acc[i][j] = __builtin_amdgcn_mfma_f32_16x16x32_bf16(ah[i], bl[j], acc[i][j], 0, 0, 0);
                    acc[i][j] = __builtin_amdgcn_mfma_f32_16x16x32_bf16(al[i], bh[j], acc[i][j], 0, 0, 0);
                }
            }

        __syncthreads();
    }

#pragma unroll
    for (int i = 0; i < FM; ++i)
#pragma unroll
        for (int j = 0; j < FN; ++j) {
            const int m = m0 + wm + i * 16 + quad * 4;
            const int n = n0 + wn + j * 16 + l15;
#pragma unroll
            for (int r = 0; r < 4; ++r) {
                const float v = acc[i][j][r];
                const long idx = (long)(m + r) * ldc + n;
                if (OUTMODE == 0) {
                    Cf[idx] = v;
                } else if (OUTMODE == 1 || OUTMODE == 3) {
                    Ch[idx] = f2bf(v);
                } else {
                    const unsigned short hi = f2bf(v);
                    Ch[idx] = hi;
                    Cl[idx] = f2bf(v - bf2f(hi));
                }
            }
        }

    if (OUTMODE == 3) {
        const int slot = (blockIdx.z * gridDim.x + blockIdx.x) * 2 + (wn >> 6);
#pragma unroll
        for (int i = 0; i < FM; ++i)
#pragma unroll
            for (int r = 0; r < 4; ++r) {
                float s = 0.f, q = 0.f;
#pragma unroll
                for (int j = 0; j < FN; ++j) {
                    const float v = acc[i][j][r];
                    s += v; q += v * v;
                }
#pragma unroll
                for (int msk = 1; msk < 16; msk <<= 1) {
                    s += __shfl_xor(s, msk, 64);
                    q += __shfl_xor(q, msk, 64);
                }
                if (l15 == 0) {
                    const int row = m0 + wm + i * 16 + quad * 4 + r;
                    S1[(long)row * 256 + slot] = s;
                    S2[(long)row * 256 + slot] = q;
                }
            }
    }
}

// ---------------- fused scores+softmax+y v6 (key-split waves in S) ----------
// 512 blocks (b = id&7, kh = (id>>3)&1, qt = id>>4), 4 waves.
// Wave w: qh = w&1 (q rows qh*32..+32), kv = w>>1 (keys kv*64..+64 per tile).
// S: per chunk, wave reads 8 phi b128 (its 64 keys) and does 24 MFMAs
//    (2 q-sets x 4 key-tiles x 3 split). theta-hi in regs; theta-lo streamed
//    from global per chunk. Softmax: per-wave partial (m,l) over 64 keys ->
//    Msh/Lsh exchange -> shared final. PV: square tiling (unchanged).
// LDS: FG 32768 + Pw2 17408 + Msh/Lsh/Aly 1280 = 51,456 B.
#define PSTRP 136   // P LDS row stride (128 keys + 8 pad)

// swizzled short-offset into a [rows][64-short] tile: 16B slot ^= row&7
__device__ __forceinline__ int swz64(int row, int slot) {
    return (row << 6) + (((slot ^ row) & 7) << 3);
}

__global__ __launch_bounds__(256, 2) void fused_attn(
    const unsigned short* __restrict__ thphH,
    const unsigned short* __restrict__ thphL,
    const unsigned short* __restrict__ gbf,
    float* __restrict__ yp,       // [2][B][N][P] fp32 partials (self-normalized)
    float2* __restrict__ ml)      // [2][B*N] {m, l}
{
    const int N = 2048, P = 256, P2 = 512;
    const int id = blockIdx.x;
    const int b  = id & 7;            // XCD-locality heuristic
    const int kh = (id >> 3) & 1;     // key half
    const int qt = id >> 4;           // 0..31
    const int q0 = qt * 64;

    const unsigned short* thB = thphH + (long)b * N * P2;
    const unsigned short* tlB = thphL + (long)b * N * P2;
    const unsigned short* gB  = gbf   + (long)b * P * N;
    float*  ypB = yp + (long)kh * (8L * N * P) + (long)b * N * P;
    float2* mlB = ml + (long)kh * (8L * N) + (long)b * N;

    // phi hi/lo and G share the same LDS (disjoint phases / halves, fenced)
    __shared__ unsigned short FG[2 * 128 * 64];       // 32,768 B
    unsigned short* Fh = FG;                          // [128][64] swizzled
    unsigned short* Fl = FG + 128 * 64;
    unsigned short* Gs = FG;                          // [256][64] swizzled
    __shared__ unsigned short Pw2[64 * PSTRP];        // P [64 q][128 key + pad]
    __shared__ float Msh[2][64], Lsh[2][64];          // per-key-half partials
    __shared__ float Aly[64];                         // per-row alpha / linv

    const int tid = threadIdx.x;
    const int wid = tid >> 6, lane = tid & 63;
    const int l15 = lane & 15, quad = lane >> 4;
    const int qh = wid & 1, kv = wid >> 1;

    // theta-HI fragments in regs: rows q0+qh*32+a*16+l15, all 8 c-chunks
    short8 tHr[2][8];
#pragma unroll
    for (int a = 0; a < 2; ++a) {
        const unsigned short* t = thB + (long)(q0 + qh * 32 + a * 16 + l15) * P2;
#pragma unroll
        for (int kc = 0; kc < 8; ++kc)
            tHr[a][kc] = *(const short8*)&t[kc * 32 + quad * 8];
    }
    // theta-LO base pointers (streamed per chunk)
    const unsigned short* tloB[2];
#pragma unroll
    for (int a = 0; a < 2; ++a)
        tloB[a] = tlB + (long)(q0 + qh * 32 + a * 16 + l15) * P2 + quad * 8;

    float mrun[2][4], lrun[2][4];
#pragma unroll
    for (int a = 0; a < 2; ++a)
#pragma unroll
        for (int r = 0; r < 4; ++r) { mrun[a][r] = -1e30f; lrun[a][r] = 0.f; }

    // oacc[g*4+pj]: rows g*16+quad*4+r, cols wid*64+pj*16+l15
    floatx4 oacc[16];
#pragma unroll
    for (int p = 0; p < 16; ++p) oacc[p] = (floatx4){0.f, 0.f, 0.f, 0.f};

    // staging: prow4 = tid>>2 (0..63), lslot = tid&3 (16B granule in 32-short half)
    const int prow4 = tid >> 2, lslot = tid & 3;
    short8 pfH[2][2], pfL[2][2];   // phi [set][s]
    short8 tLo[2][2];              // theta-lo [set][a]
    short8 pg[2][4];

    for (int mt = 0; mt < 8; ++mt) {
        const int m0 = kh * 1024 + mt * 128;

        // ---- S phase: 8 chunks of 32 c, half-column dbuf ----
        floatx4 sacc[2][4];
#pragma unroll
        for (int a = 0; a < 2; ++a)
#pragma unroll
            for (int kt = 0; kt < 4; ++kt) sacc[a][kt] = (floatx4){0.f, 0.f, 0.f, 0.f};

        // prologue: phi chunk0 -> half0 (prev PV mc3 read logical half1 —
        // disjoint per-row under bijective swizzle), prefetch chunk1 + tlo0.
#pragma unroll
        for (int s = 0; s < 2; ++s) {
            const long o = (long)(m0 + s * 64 + prow4) * P2 + P + 0 * 32 + lslot * 8;
            pfH[0][s] = *(const short8*)&thB[o];
            pfL[0][s] = *(const short8*)&tlB[o];
        }
#pragma unroll
        for (int s = 0; s < 2; ++s) {
            const int row = s * 64 + prow4;
            *(short8*)&Fh[swz64(row, lslot)] = pfH[0][s];
            *(short8*)&Fl[swz64(row, lslot)] = pfL[0][s];
        }
#pragma unroll
        for (int s = 0; s < 2; ++s) {
            const long o = (long)(m0 + s * 64 + prow4) * P2 + P + 1 * 32 + lslot * 8;
            pfH[1][s] = *(const short8*)&thB[o];
            pfL[1][s] = *(const short8*)&tlB[o];
        }
#pragma unroll
        for (int a = 0; a < 2; ++a) tLo[0][a] = *(const short8*)&tloB[a][0 * 32];
        __syncthreads();

#pragma unroll
        for (int kc = 0; kc < 8; ++kc) {
            if (kc < 6) {                        // prefetch phi chunk kc+2
#pragma unroll
                for (int s = 0; s < 2; ++s) {
                    const long o = (long)(m0 + s * 64 + prow4) * P2 + P + (kc + 2) * 32 + lslot * 8;
                    pfH[kc & 1][s] = *(const short8*)&thB[o];
                    pfL[kc & 1][s] = *(const short8*)&tlB[o];
                }
            }
            if (kc < 7) {                        // prefetch theta-lo chunk kc+1
#pragma unroll
                for (int a = 0; a < 2; ++a)
                    tLo[(kc + 1) & 1][a] = *(const short8*)&tloB[a][(kc + 1) * 32];
            }
            const int half = (kc & 1) * 4;
            __builtin_amdgcn_s_setprio(1);
#pragma unroll
            for (int kt = 0; kt < 4; ++kt) {
                const int ro = swz64(kv * 64 + kt * 16 + l15, half + quad);
                const short8 bh = *(const short8*)&Fh[ro];
                const short8 bl = *(const short8*)&Fl[ro];
#pragma unroll
                for (int a = 0; a < 2; ++a) {
                    sacc[a][kt] = __builtin_amdgcn_mfma_f32_16x16x32_bf16(tHr[a][kc], bh, sacc[a][kt], 0, 0, 0);
                    sacc[a][kt] = __builtin_amdgcn_mfma_f32_16x16x32_bf16(tHr[a][kc], bl, sacc[a][kt], 0, 0, 0);
                    sacc[a][kt] = __builtin_amdgcn_mfma_f32_16x16x32_bf16(tLo[kc & 1][a], bh, sacc[a][kt], 0, 0, 0);
                }
            }
            __builtin_amdgcn_s_setprio(0);
            if (kc < 7) {                        // write phi chunk kc+1 into other half
                const int wh = ((kc + 1) & 1) * 4;
#pragma unroll
                for (int s = 0; s < 2; ++s) {
                    const int row = s * 64 + prow4;
                    *(short8*)&Fh[swz64(row, wh + lslot)] = pfH[(kc + 1) & 1][s];
                    *(short8*)&Fl[swz64(row, wh + lslot)] = pfL[(kc + 1) & 1][s];
                }
            }
            __syncthreads();
        }

        // ---- softmax stage 1: per-wave partial max over 64 keys ----
#pragma unroll
        for (int a = 0; a < 2; ++a)
#pragma unroll
            for (int r = 0; r < 4; ++r) {
                float v = sacc[a][0][r];
#pragma unroll
                for (int kt = 1; kt < 4; ++kt) v = fmaxf(v, sacc[a][kt][r]);
                v = fmaxf(v, __shfl_xor(v, 1, 64));
                v = fmaxf(v, __shfl_xor(v, 2, 64));
                v = fmaxf(v, __shfl_xor(v, 4, 64));
                v = fmaxf(v, __shfl_xor(v, 8, 64));
                if (l15 == 0) Msh[kv][qh * 32 + a * 16 + quad * 4 + r] = v;
            }
        __syncthreads();

        // ---- softmax stage 2: shared m; P + partial l ----
        float alpha[2][4];
#pragma unroll
        for (int a = 0; a < 2; ++a)
#pragma unroll
            for (int r = 0; r < 4; ++r) {
                const int row = qh * 32 + a * 16 + quad * 4 + r;
                const float vm = fmaxf(Msh[0][row], Msh[1][row]);
                const float mo = mrun[a][r];
                const float mn = fmaxf(mo, vm);
                mrun[a][r] = mn;
                alpha[a][r] = __expf(mo - mn);
            }
        float lpart[2][4];
#pragma unroll
        for (int a = 0; a < 2; ++a)
#pragma unroll
            for (int r = 0; r < 4; ++r) lpart[a][r] = 0.f;
#pragma unroll
        for (int a = 0; a < 2; ++a)
#pragma unroll
            for (int kt = 0; kt < 4; ++kt)
#pragma unroll
                for (int r = 0; r < 4; ++r) {
                    const float p = __expf(sacc[a][kt][r] - mrun[a][r]);
                    Pw2[(qh * 32 + a * 16 + quad * 4 + r) * PSTRP + kv * 64 + kt * 16 + l15] = f2bf(p);
                    lpart[a][r] += p;
                }
#pragma unroll
        for (int a = 0; a < 2; ++a)
#pragma unroll
            for (int r = 0; r < 4; ++r) {
                float s = lpart[a][r];
                s += __shfl_xor(s, 1, 64);
                s += __shfl_xor(s, 2, 64);
                s += __shfl_xor(s, 4, 64);
                s += __shfl_xor(s, 8, 64);
                if (l15 == 0) Lsh[kv][qh * 32 + a * 16 + quad * 4 + r] = s;
            }
        if (kv == 0 && l15 == 0) {
#pragma unroll
            for (int a = 0; a < 2; ++a)
#pragma unroll
                for (int r = 0; r < 4; ++r)
                    Aly[qh * 32 + a * 16 + quad * 4 + r] = alpha[a][r];
        }

        // ---- PV phase: square tiling, 4 chunks of 32 keys, half dbuf ----
#pragma unroll
        for (int s = 0; s < 4; ++s)
            pg[0][s] = *(const short8*)&gB[(long)(s * 64 + prow4) * N + m0 + 0 * 32 + lslot * 8];
#pragma unroll
        for (int s = 0; s < 4; ++s)
            *(short8*)&Gs[swz64(s * 64 + prow4, lslot)] = pg[0][s];
#pragma unroll
        for (int s = 0; s < 4; ++s)
            pg[1][s] = *(const short8*)&gB[(long)(s * 64 + prow4) * N + m0 + 1 * 32 + lslot * 8];
        __syncthreads();   // G0 + Pw2 + Lsh + Aly visible

        // lrun update with full-tile l
#pragma unroll
        for (int a = 0; a < 2; ++a)
#pragma unroll
            for (int r = 0; r < 4; ++r) {
                const int row = qh * 32 + a * 16 + quad * 4 + r;
                const float lt = Lsh[0][row] + Lsh[1][row];
                lrun[a][r] = lrun[a][r] * alpha[a][r] + lt;
            }

        float alr[4][4];
#pragma unroll
        for (int g = 0; g < 4; ++g)
#pragma unroll
            for (int r = 0; r < 4; ++r) alr[g][r] = Aly[g * 16 + quad * 4 + r];
        int noresc = 1;
#pragma unroll
        for (int g = 0; g < 4; ++g)
#pragma unroll
            for (int r = 0; r < 4; ++r) noresc &= (alr[g][r] == 1.f);
        if (!__all(noresc)) {
#pragma unroll
            for (int g = 0; g < 4; ++g)
#pragma unroll
                for (int pj = 0; pj < 4; ++pj)
#pragma unroll
                    for (int r = 0; r < 4; ++r) oacc[g * 4 + pj][r] *= alr[g][r];
        }

#pragma unroll
        for (int mc = 0; mc < 4; ++mc) {
            if (mc < 2) {                        // prefetch chunk mc+2 into set mc&1
#pragma unroll
                for (int s = 0; s < 4; ++s)
                    pg[mc & 1][s] = *(const short8*)&gB[(long)(s * 64 + prow4) * N + m0 + (mc + 2) * 32 + lslot * 8];
            }
            const int half = (mc & 1) * 4;
            short8 af[4];
#pragma unroll
            for (int g = 0; g < 4; ++g)
                af[g] = *(const short8*)&Pw2[(g * 16 + l15) * PSTRP + mc * 32 + quad * 8];
            __builtin_amdgcn_s_setprio(1);
#pragma unroll
            for (int pj = 0; pj < 4; ++pj) {
                const short8 bg = *(const short8*)&Gs[swz64(wid * 64 + pj * 16 + l15, half + quad)];
#pragma unroll
                for (int g = 0; g < 4; ++g)
                    oacc[g * 4 + pj] = __builtin_amdgcn_mfma_f32_16x16x32_bf16(af[g], bg, oacc[g * 4 + pj], 0, 0, 0);
            }
            __builtin_amdgcn_s_setprio(0);
            if (mc < 3) {                        // write chunk mc+1 into other half
                const int wh = ((mc + 1) & 1) * 4;
#pragma unroll
                for (int s = 0; s < 4; ++s)
                    *(short8*)&Gs[swz64(s * 64 + prow4, wh + lslot)] = pg[(mc + 1) & 1][s];
                __syncthreads();
            }
        }
    }

    // ---- finalize: publish 1/l, scale, write fp32 partial + (m,l) ----
    if (kv == 0 && l15 == 0) {
#pragma unroll
        for (int a = 0; a < 2; ++a)
#pragma unroll
            for (int r = 0; r < 4; ++r)
                Aly[qh * 32 + a * 16 + quad * 4 + r] = 1.0f / lrun[a][r];
    }
    __syncthreads();
    float liv[4][4];
#pragma unroll
    for (int g = 0; g < 4; ++g)
#pragma unroll
        for (int r = 0; r < 4; ++r) liv[g][r] = Aly[g * 16 + quad * 4 + r];
#pragma unroll
    for (int g = 0; g < 4; ++g)
#pragma unroll
        for (int pj = 0; pj < 4; ++pj)
#pragma unroll
            for (int r = 0; r < 4; ++r) {
                const int row = q0 + g * 16 + quad * 4 + r;
                const int col = wid * 64 + pj * 16 + l15;
                ypB[(long)row * P + col] = oacc[g * 4 + pj][r] * liv[g][r];
            }
    if (kv == 0 && l15 == 0) {
#pragma unroll
        for (int a = 0; a < 2; ++a)
#pragma unroll
            for (int r = 0; r < 4; ++r) {
                const int row = q0 + qh * 32 + a * 16 + quad * 4 + r;
                mlB[row] = float2{mrun[a][r], lrun[a][r]};
            }
    }
}

// merge the two key-half partials: y = f1*y1 + f2*y2, f_i = l_i e^{m_i-m}/Z
__global__ __launch_bounds__(256) void attn_merge(
    const float* __restrict__ yp, const float2* __restrict__ ml,
    unsigned short* __restrict__ ybf)
{
    const long HALF = 8L * 2048 * 256;
    const long t = (long)blockIdx.x * 256 + threadIdx.x;
    const long row = t >> 5;
    const int  c0  = ((int)t & 31) * 8;
    const float2 a = ml[row];
    const float2 c = ml[8L * 2048 + row];
    const float mx = fmaxf(a.x, c.x);
    const float w1 = a.y * __expf(a.x - mx);
    const float w2 = c.y * __expf(c.x - mx);
    const float inv = 1.0f / (w1 + w2);
    const float f1 = w1 * inv, f2 = w2 * inv;
    const long base = row * 256 + c0;
    const float4 u0 = *(const float4*)&yp[base];
    const float4 u1 = *(const float4*)&yp[base + 4];
    const float4 v0 = *(const float4*)&yp[HALF + base];
    const float4 v1 = *(const float4*)&yp[HALF + base + 4];
    ushort4 o0, o1;
    o0.x = f2bf(f1 * u0.x + f2 * v0.x);
    o0.y = f2bf(f1 * u0.y + f2 * v0.y);
    o0.z = f2bf(f1 * u0.z + f2 * v0.z);
    o0.w = f2bf(f1 * u0.w + f2 * v0.w);
    o1.x = f2bf(f1 * u1.x + f2 * v1.x);
    o1.y = f2bf(f1 * u1.y + f2 * v1.y);
    o1.z = f2bf(f1 * u1.z + f2 * v1.z);
    o1.w = f2bf(f1 * u1.w + f2 * v1.w);
    *(ushort4*)&ybf[base] = o0;
    *(ushort4*)&ybf[base + 4] = o1;
}

// ---------------- BN finalize + apply ----------------
__global__ __launch_bounds__(256) void bn_finalize(
    const float* __restrict__ p1, const float* __restrict__ p2,
    float* __restrict__ mean, float* __restrict__ rstd, float cnt)
{
    const int c = blockIdx.x, t = threadIdx.x;
    __shared__ float rs[256], rq[256];
    rs[t] = p1[(long)c * 256 + t];
    rq[t] = p2[(long)c * 256 + t];
    __syncthreads();
    for (int st = 128; st > 0; st >>= 1) {
        if (t < st) { rs[t] += rs[t + st]; rq[t] += rq[t + st]; }
        __syncthreads();
    }
    if (t == 0) {
        const float m = rs[0] / cnt;
        mean[c] = m;
        rstd[c] = rsqrtf(rq[0] / cnt - m * m + 1e-5f);
    }
}

__global__ __launch_bounds__(256) void bn_apply_bf(
    const unsigned short* __restrict__ z, const float* __restrict__ x,
    const float* __restrict__ mean, const float* __restrict__ rstd,
    const float* __restrict__ gamma, const float* __restrict__ beta,
    float* __restrict__ out, int C, int N)
{
    const long i = ((long)blockIdx.x * 256 + threadIdx.x) * 8;
    const int c = (int)((i / N) % C);
    const float mu = mean[c], rs = rstd[c], ga = gamma[c], be = beta[c];
    const ushort4 z0 = *(const ushort4*)&z[i];
    const ushort4 z1 = *(const ushort4*)&z[i + 4];
    const float4 x0 = *(const float4*)&x[i];
    const float4 x1 = *(const float4*)&x[i + 4];
    float4 o0, o1;
    o0.x = (bf2f(z0.x) - mu) * rs * ga + be + x0.x;
    o0.y = (bf2f(z0.y) - mu) * rs * ga + be + x0.y;
    o0.z = (bf2f(z0.z) - mu) * rs * ga + be + x0.z;
    o0.w = (bf2f(z0.w) - mu) * rs * ga + be + x0.w;
    o1.x = (bf2f(z1.x) - mu) * rs * ga + be + x1.x;
    o1.y = (bf2f(z1.y) - mu) * rs * ga + be + x1.y;
    o1.z = (bf2f(z1.z) - mu) * rs * ga + be + x1.z;
    o1.w = (bf2f(z1.w) - mu) * rs * ga + be + x1.w;
    *(float4*)&out[i] = o0;
    *(float4*)&out[i + 4] = o1;
}

extern "C" void kernel_launch(void* const* d_in, const int* in_sizes, int n_in,
                              void* d_out, int out_size, void* d_ws, size_t ws_size,
                              hipStream_t stream)
{
    const int B = 8, C = 512, N = 2048, P = 256;
    const float* x      = (const float*)d_in[0];
    const float* Wg     = (const float*)d_in[1];
    const float* Wtheta = (const float*)d_in[2];
    const float* Wphi   = (const float*)d_in[3];
    const float* Wz     = (const float*)d_in[4];
    const float* gamma  = (const float*)d_in[5];
    const float* beta   = (const float*)d_in[6];
    float* out = (float*)d_out;

    // ---- workspace layout (float units), same as round 9 ----
    float* ws = (float*)d_ws;
    const long NCle = (long)N * C;            // 1,048,576 per batch (= N*2P)
    const long NP   = (long)N * P;            // 524,288 per batch
    const long R0   = (long)B * NCle;         // 8.39M floats
    unsigned short* xtH   = (unsigned short*)ws;                // B*N*C
    unsigned short* xtL   = xtH + B * NCle;
    unsigned short* zbf   = (unsigned short*)ws;                // aliases xt (dead)
    unsigned short* thphH = (unsigned short*)(ws + R0);         // B*N*2P
    unsigned short* thphL = thphH + B * NCle;                   // B*N*2P
    unsigned short* gbf   = (unsigned short*)(ws + 2 * R0);     // B*P*N
    unsigned short* fbf   = gbf + B * NP;                       // attn partial region
    unsigned short* ybf   = fbf + (long)B * N * N;              // B*N*P
    unsigned short* W2H   = ybf + B * NP;                       // 2P*C
    unsigned short* W2L   = W2H + 2L * P * C;
    unsigned short* WgB   = W2L + 2L * P * C;                   // P*C
    unsigned short* WzB   = WgB + (long)P * C;
    // attn split-K partials in the dead fbf region; ml in dead xtL region.
    float*          yp    = (float*)fbf;                        // [2][B][N][P] fp32
    float2*         ml    = (float2*)(ws + 6L * 1024 * 1024);   // [2][B*N], in xtL
    // BN scratch aliases thph region (dead after fused_attn): [C][256] x2
    float*          bnp1  = ws + R0;
    float*          bnp2  = bnp1 + (long)C * 256;
    float*          mean  = bnp2 + (long)C * 256;
    float*          rstd  = mean + C;

    const long sX = (long)C * N;
    const int  P2 = 2 * P;

    // 1: transpose+split x -> xT hi/lo [B][N][C]
    transpose_split<<<dim3(N / 32, C / 32, B), 256, 0, stream>>>(x, xtH, xtL, C, N);
    // 2: weight preps
    split_w2<<<(2 * P * C + 255) / 256, 256, 0, stream>>>(Wtheta, Wphi, W2H, W2L, P * C);
    cast_bf16<<<P * C / 1024, 256, 0, stream>>>(Wg, WgB);
    cast_bf16<<<P * C / 1024, 256, 0, stream>>>(Wz, WzB);

    // 3: thph [B][N][2P] = xT @ W2^T (split in/out); 128x128, 512 blocks
    mfma_gemm<true, 2, 4, 4><<<dim3(P2 / 128, N / 128, B), 256, 0, stream>>>(
        xtH, xtL, W2H, W2L, thphH, thphL, C, C, C, P2, NCle, 0, NCle, nullptr, nullptr);
    // 4: g [B][P][N] = Wg @ xT^T (plain, bf16 out); 64x128, 512 blocks
    mfma_gemm<false, 1, 2, 4><<<dim3(N / 128, P / 64, B), 256, 0, stream>>>(
        WgB, WgB, xtH, xtH, gbf, gbf, C, C, C, N, 0, NCle, NP, nullptr, nullptr);

    // 5: fused scores+softmax+y, split-K x2 over keys (512 blocks, 2/CU) + merge
    fused_attn<<<dim3(512), 256, 0, stream>>>(thphH, thphL, gbf, yp, ml);
    attn_merge<<<dim3(2048), 256, 0, stream>>>(yp, ml, ybf);

    // 6: z [B][C][N] bf16 = Wz @ yT^T, BN partials (thph dead now)
    mfma_gemm<false, 3, 4, 4><<<dim3(N / 128, C / 128, B), 256, 0, stream>>>(
        WzB, WzB, ybf, ybf, zbf, zbf, P, P, P, N, 0, NP, sX, bnp1, bnp2);

    // 7: BN finalize + apply + residual
    bn_finalize<<<C, 256, 0, stream>>>(bnp1, bnp2, mean, rstd, (float)B * N);
    bn_apply_bf<<<(int)((B * sX) / 2048), 256, 0, stream>>>(zbf, x, mean, rstd, gamma, beta, out, C, N);
}

// Round 7
// 337.769 us; speedup vs baseline: 1.0539x; 1.0539x over previous
//
#include <hip/hip_runtime.h>
#include <hip/hip_bf16.h>

// B=8, C=512, N=2048, P=256.
// Round 17: R6 spill fix — ONE variable changed: __launch_bounds__(256,2) ->
// (256,1). R6's FETCH 202MB / WRITE 81MB / MfmaUtil 15 was scratch spill:
// the v6 live set (~200 VGPR) exceeded the 128 cap that min-waves=2 imposes.
// Occupancy is LDS-limited to 2 blocks/CU (= 2 waves/SIMD) anyway, and VGPR
// in (128,256] gives the SAME 2 waves/SIMD -> min-waves=1 frees registers
// at zero occupancy cost. This actually tests the key-split-wave structure
// (phi multicast 4x -> 2x, the dominant S-phase LDS term).
// Predicted: VGPR ~180-230 (diagnostic), FETCH ~25-30MB, WRITE 33MB,
// MfmaUtil ~35, fused 186 -> ~80us, total ~245us.

typedef __attribute__((ext_vector_type(8))) short short8;
typedef __attribute__((ext_vector_type(4))) float floatx4;

// ---------------- bf16 helpers ----------------
__device__ __forceinline__ unsigned short f2bf(float v) {
    __hip_bfloat16 h = __float2bfloat16(v);
    return *(unsigned short*)&h;
}
__device__ __forceinline__ float bf2f(unsigned short u) {
    __hip_bfloat16 h;
    *(unsigned short*)&h = u;
    return __bfloat162float(h);
}

// async global->LDS 16B per lane (dest must be wave-linear: base + lane*16)
__device__ __forceinline__ void gl16(const unsigned short* g, unsigned short* l) {
    __builtin_amdgcn_global_load_lds(
        (const __attribute__((address_space(1))) unsigned int*)g,
        (__attribute__((address_space(3))) unsigned int*)l, 16, 0, 0);
}

// transpose + hi/lo split: X [R][N] fp32 -> Thi/Tlo [N][R] bf16 (batched over z)
__global__ __launch_bounds__(256) void transpose_split(
    const float* __restrict__ X, unsigned short* __restrict__ Thi,
    unsigned short* __restrict__ Tlo, int R, int N)
{
    X   += (long)blockIdx.z * R * N;
    Thi += (long)blockIdx.z * N * R;
    Tlo += (long)blockIdx.z * N * R;
    __shared__ float s[32][33];
    const int tx = threadIdx.x & 31, ty = threadIdx.x >> 5;
    const int n0 = blockIdx.x * 32, r0 = blockIdx.y * 32;
#pragma unroll
    for (int r = 0; r < 4; ++r)
        s[ty + r * 8][tx] = X[(long)(r0 + ty + r * 8) * N + n0 + tx];
    __syncthreads();
#pragma unroll
    for (int r = 0; r < 4; ++r) {
        const int n = ty + r * 8;
        const float v = s[tx][n];
        const unsigned short hi = f2bf(v);
        const unsigned short lo = f2bf(v - bf2f(hi));
        Thi[(long)(n0 + n) * R + r0 + tx] = hi;
        Tlo[(long)(n0 + n) * R + r0 + tx] = lo;
    }
}

// concat [Wth; Wph] rows and hi/lo split: out [2P][C]
__global__ __launch_bounds__(256) void split_w2(
    const float* __restrict__ Wth, const float* __restrict__ Wph,
    unsigned short* __restrict__ Whi, unsigned short* __restrict__ Wlo, int PC)
{
    const int i = blockIdx.x * 256 + threadIdx.x;
    if (i < 2 * PC) {
        const float v = (i < PC) ? Wth[i] : Wph[i - PC];
        const unsigned short hi = f2bf(v);
        Whi[i] = hi;
        Wlo[i] = f2bf(v - bf2f(hi));
    }
}

__global__ __launch_bounds__(256) void cast_bf16(
    const float* __restrict__ X, unsigned short* __restrict__ Y)
{
    const long i = ((long)blockIdx.x * 256 + threadIdx.x) * 4;
    const float4 v = *(const float4*)&X[i];
    ushort4 o;
    o.x = f2bf(v.x); o.y = f2bf(v.y); o.z = f2bf(v.z); o.w = f2bf(v.w);
    *(ushort4*)&Y[i] = o;
}

// ---------------- MFMA GEMM (async global_load_lds, double-buffered) ----------
// C[M][N] = A[M][K] * B[N][K]^T, bf16 K-contiguous inputs, fp32 accum.
// OUTMODE: 0 fp32, 1 bf16, 2 hi/lo split bf16, 3 bf16 + BN partials scratch
//          (slot = (bz*gridDim.x+bx)*2 + (wn>>6); [C][256] scratch).
#define BK 32

template <bool SPLIT, int OUTMODE, int FM, int FN>
__global__ __launch_bounds__(256) void mfma_gemm(
    const unsigned short* __restrict__ Ahi, const unsigned short* __restrict__ Alo,
    const unsigned short* __restrict__ Bhi, const unsigned short* __restrict__ Blo,
    void* __restrict__ Cout, void* __restrict__ Cout2,
    int K, int lda, int ldb, int ldc,
    long sA, long sB, long sC,
    float* __restrict__ S1, float* __restrict__ S2)
{
    constexpr int MTM = FM * 32, MTN = FN * 32;
    constexpr int SA = FM / 2, SB = FN / 2;
    constexpr int ASZ = MTM * BK, BSZ = MTN * BK;

    Ahi += (long)blockIdx.z * sA;
    Bhi += (long)blockIdx.z * sB;
    if (SPLIT) { Alo += (long)blockIdx.z * sA; Blo += (long)blockIdx.z * sB; }
    float* Cf = (float*)Cout + (long)blockIdx.z * sC;
    unsigned short* Ch = (unsigned short*)Cout + (long)blockIdx.z * sC;
    unsigned short* Cl = (unsigned short*)Cout2 + (long)blockIdx.z * sC;

    __shared__ unsigned short AsH[2 * ASZ], BsH[2 * BSZ];
    __shared__ unsigned short AsL[SPLIT ? 2 * ASZ : 8], BsL[SPLIT ? 2 * BSZ : 8];

    const int tid = threadIdx.x;
    const int wid = tid >> 6, lane = tid & 63;
    const int wm = (wid >> 1) * (FM * 16), wn = (wid & 1) * (FN * 16);
    const int l15 = lane & 15, quad = lane >> 4;
    const int m0 = blockIdx.y * MTM, n0 = blockIdx.x * MTN;

    int arow[SA], acol[SA], brow[SB], bcol[SB];
#pragma unroll
    for (int t = 0; t < SA; ++t) {
        const int gid = t * 256 + tid;
        arow[t] = gid >> 2; acol[t] = (gid & 3) * 8;
    }
#pragma unroll
    for (int t = 0; t < SB; ++t) {
        const int gid = t * 256 + tid;
        brow[t] = gid >> 2; bcol[t] = (gid & 3) * 8;
    }

    auto stage = [&](int k0, int buf) {
#pragma unroll
        for (int t = 0; t < SA; ++t) {
            const long o = (long)(m0 + arow[t]) * lda + k0 + acol[t];
            const int d = buf * ASZ + (t * 256 + tid) * 8;
            gl16(&Ahi[o], &AsH[d]);
            if (SPLIT) gl16(&Alo[o], &AsL[d]);
        }
#pragma unroll
        for (int t = 0; t < SB; ++t) {
            const long o = (long)(n0 + brow[t]) * ldb + k0 + bcol[t];
            const int d = buf * BSZ + (t * 256 + tid) * 8;
            gl16(&Bhi[o], &BsH[d]);
            if (SPLIT) gl16(&Blo[o], &BsL[d]);
        }
    };

    floatx4 acc[FM][FN];
#pragma unroll
    for (int i = 0; i < FM; ++i)
#pragma unroll
        for (int j = 0; j < FN; ++j) acc[i][j] = (floatx4){0.f, 0.f, 0.f, 0.f};

    const int iters = K / BK;
    stage(0, 0);
    __syncthreads();

    for (int it = 0; it < iters; ++it) {
        const int cur = it & 1;
        if (it + 1 < iters) stage((it + 1) * BK, cur ^ 1);

        short8 ah[FM], bh[FN], al[SPLIT ? FM : 1], bl[SPLIT ? FN : 1];
#pragma unroll
        for (int i = 0; i < FM; ++i) {
            ah[i] = *(const short8*)&AsH[cur * ASZ + (wm + i * 16 + l15) * BK + quad * 8];
            if (SPLIT) al[i] = *(const short8*)&AsL[cur * ASZ + (wm + i * 16 + l15) * BK + quad * 8];
        }
#pragma unroll
        for (int j = 0; j < FN; ++j) {
            bh[j] = *(const short8*)&BsH[cur * BSZ + (wn + j * 16 + l15) * BK + quad * 8];
            if (SPLIT) bl[j] = *(const short8*)&BsL[cur * BSZ + (wn + j * 16 + l15) * BK + quad * 8];
        }
#pragma unroll
        for (int i = 0; i < FM; ++i)
#pragma unroll
            for (int j = 0; j < FN; ++j) {
                acc[i][j] = __builtin_amdgcn_mfma_f32_16x16x32_bf16(ah[i], bh[j], acc[i][j], 0, 0, 0);
                if (SPLIT) {
                    acc[i][j] = __builtin_amdgcn_mfma_f32_16x16x32_bf16(ah[i], bl[j], acc[i][j], 0, 0, 0);
                    acc[i][j] = __builtin_amdgcn_mfma_f32_16x16x32_bf16(al[i], bh[j], acc[i][j], 0, 0, 0);
                }
            }

        __syncthreads();
    }

#pragma unroll
    for (int i = 0; i < FM; ++i)
#pragma unroll
        for (int j = 0; j < FN; ++j) {
            const int m = m0 + wm + i * 16 + quad * 4;
            const int n = n0 + wn + j * 16 + l15;
#pragma unroll
            for (int r = 0; r < 4; ++r) {
                const float v = acc[i][j][r];
                const long idx = (long)(m + r) * ldc + n;
                if (OUTMODE == 0) {
                    Cf[idx] = v;
                } else if (OUTMODE == 1 || OUTMODE == 3) {
                    Ch[idx] = f2bf(v);
                } else {
                    const unsigned short hi = f2bf(v);
                    Ch[idx] = hi;
                    Cl[idx] = f2bf(v - bf2f(hi));
                }
            }
        }

    if (OUTMODE == 3) {
        const int slot = (blockIdx.z * gridDim.x + blockIdx.x) * 2 + (wn >> 6);
#pragma unroll
        for (int i = 0; i < FM; ++i)
#pragma unroll
            for (int r = 0; r < 4; ++r) {
                float s = 0.f, q = 0.f;
#pragma unroll
                for (int j = 0; j < FN; ++j) {
                    const float v = acc[i][j][r];
                    s += v; q += v * v;
                }
#pragma unroll
                for (int msk = 1; msk < 16; msk <<= 1) {
                    s += __shfl_xor(s, msk, 64);
                    q += __shfl_xor(q, msk, 64);
                }
                if (l15 == 0) {
                    const int row = m0 + wm + i * 16 + quad * 4 + r;
                    S1[(long)row * 256 + slot] = s;
                    S2[(long)row * 256 + slot] = q;
                }
            }
    }
}

// ---------------- fused scores+softmax+y v6.1 (key-split waves, regs freed) ----
// 512 blocks (b = id&7, kh = (id>>3)&1, qt = id>>4), 4 waves.
// Wave w: qh = w&1 (q rows qh*32..+32), kv = w>>1 (keys kv*64..+64 per tile).
// S: per chunk, wave reads 8 phi b128 (its 64 keys) and does 24 MFMAs.
//    theta-hi in regs; theta-lo streamed from global per chunk.
//    Softmax two-stage via Msh/Lsh. PV: square tiling (unchanged).
// LDS: FG 32768 + Pw2 17408 + Msh/Lsh/Aly 1280 = 51,456 B -> 2 blocks/CU.
#define PSTRP 136   // P LDS row stride (128 keys + 8 pad)

// swizzled short-offset into a [rows][64-short] tile: 16B slot ^= row&7
__device__ __forceinline__ int swz64(int row, int slot) {
    return (row << 6) + (((slot ^ row) & 7) << 3);
}

__global__ __launch_bounds__(256, 1) void fused_attn(
    const unsigned short* __restrict__ thphH,
    const unsigned short* __restrict__ thphL,
    const unsigned short* __restrict__ gbf,
    float* __restrict__ yp,       // [2][B][N][P] fp32 partials (self-normalized)
    float2* __restrict__ ml)      // [2][B*N] {m, l}
{
    const int N = 2048, P = 256, P2 = 512;
    const int id = blockIdx.x;
    const int b  = id & 7;            // XCD-locality heuristic
    const int kh = (id >> 3) & 1;     // key half
    const int qt = id >> 4;           // 0..31
    const int q0 = qt * 64;

    const unsigned short* thB = thphH + (long)b * N * P2;
    const unsigned short* tlB = thphL + (long)b * N * P2;
    const unsigned short* gB  = gbf   + (long)b * P * N;
    float*  ypB = yp + (long)kh * (8L * N * P) + (long)b * N * P;
    float2* mlB = ml + (long)kh * (8L * N) + (long)b * N;

    // phi hi/lo and G share the same LDS (disjoint phases / halves, fenced)
    __shared__ unsigned short FG[2 * 128 * 64];       // 32,768 B
    unsigned short* Fh = FG;                          // [128][64] swizzled
    unsigned short* Fl = FG + 128 * 64;
    unsigned short* Gs = FG;                          // [256][64] swizzled
    __shared__ unsigned short Pw2[64 * PSTRP];        // P [64 q][128 key + pad]
    __shared__ float Msh[2][64], Lsh[2][64];          // per-key-half partials
    __shared__ float Aly[64];                         // per-row alpha / linv

    const int tid = threadIdx.x;
    const int wid = tid >> 6, lane = tid & 63;
    const int l15 = lane & 15, quad = lane >> 4;
    const int qh = wid & 1, kv = wid >> 1;

    // theta-HI fragments in regs: rows q0+qh*32+a*16+l15, all 8 c-chunks
    short8 tHr[2][8];
#pragma unroll
    for (int a = 0; a < 2; ++a) {
        const unsigned short* t = thB + (long)(q0 + qh * 32 + a * 16 + l15) * P2;
#pragma unroll
        for (int kc = 0; kc < 8; ++kc)
            tHr[a][kc] = *(const short8*)&t[kc * 32 + quad * 8];
    }
    // theta-LO base pointers (streamed per chunk)
    const unsigned short* tloB[2];
#pragma unroll
    for (int a = 0; a < 2; ++a)
        tloB[a] = tlB + (long)(q0 + qh * 32 + a * 16 + l15) * P2 + quad * 8;

    float mrun[2][4], lrun[2][4];
#pragma unroll
    for (int a = 0; a < 2; ++a)
#pragma unroll
        for (int r = 0; r < 4; ++r) { mrun[a][r] = -1e30f; lrun[a][r] = 0.f; }

    // oacc[g*4+pj]: rows g*16+quad*4+r, cols wid*64+pj*16+l15
    floatx4 oacc[16];
#pragma unroll
    for (int p = 0; p < 16; ++p) oacc[p] = (floatx4){0.f, 0.f, 0.f, 0.f};

    // staging: prow4 = tid>>2 (0..63), lslot = tid&3 (16B granule in 32-short half)
    const int prow4 = tid >> 2, lslot = tid & 3;
    short8 pfH[2][2], pfL[2][2];   // phi [set][s]
    short8 tLo[2][2];              // theta-lo [set][a]
    short8 pg[2][4];

    for (int mt = 0; mt < 8; ++mt) {
        const int m0 = kh * 1024 + mt * 128;

        // ---- S phase: 8 chunks of 32 c, half-column dbuf ----
        floatx4 sacc[2][4];
#pragma unroll
        for (int a = 0; a < 2; ++a)
#pragma unroll
            for (int kt = 0; kt < 4; ++kt) sacc[a][kt] = (floatx4){0.f, 0.f, 0.f, 0.f};

        // prologue: phi chunk0 -> half0, prefetch chunk1 + tlo0.
#pragma unroll
        for (int s = 0; s < 2; ++s) {
            const long o = (long)(m0 + s * 64 + prow4) * P2 + P + 0 * 32 + lslot * 8;
            pfH[0][s] = *(const short8*)&thB[o];
            pfL[0][s] = *(const short8*)&tlB[o];
        }
#pragma unroll
        for (int s = 0; s < 2; ++s) {
            const int row = s * 64 + prow4;
            *(short8*)&Fh[swz64(row, lslot)] = pfH[0][s];
            *(short8*)&Fl[swz64(row, lslot)] = pfL[0][s];
        }
#pragma unroll
        for (int s = 0; s < 2; ++s) {
            const long o = (long)(m0 + s * 64 + prow4) * P2 + P + 1 * 32 + lslot * 8;
            pfH[1][s] = *(const short8*)&thB[o];
            pfL[1][s] = *(const short8*)&tlB[o];
        }
#pragma unroll
        for (int a = 0; a < 2; ++a) tLo[0][a] = *(const short8*)&tloB[a][0 * 32];
        __syncthreads();

#pragma unroll
        for (int kc = 0; kc < 8; ++kc) {
            if (kc < 6) {                        // prefetch phi chunk kc+2
#pragma unroll
                for (int s = 0; s < 2; ++s) {
                    const long o = (long)(m0 + s * 64 + prow4) * P2 + P + (kc + 2) * 32 + lslot * 8;
                    pfH[kc & 1][s] = *(const short8*)&thB[o];
                    pfL[kc & 1][s] = *(const short8*)&tlB[o];
                }
            }
            if (kc < 7) {                        // prefetch theta-lo chunk kc+1
#pragma unroll
                for (int a = 0; a < 2; ++a)
                    tLo[(kc + 1) & 1][a] = *(const short8*)&tloB[a][(kc + 1) * 32];
            }
            const int half = (kc & 1) * 4;
            __builtin_amdgcn_s_setprio(1);
#pragma unroll
            for (int kt = 0; kt < 4; ++kt) {
                const int ro = swz64(kv * 64 + kt * 16 + l15, half + quad);
                const short8 bh = *(const short8*)&Fh[ro];
                const short8 bl = *(const short8*)&Fl[ro];
#pragma unroll
                for (int a = 0; a < 2; ++a) {
                    sacc[a][kt] = __builtin_amdgcn_mfma_f32_16x16x32_bf16(tHr[a][kc], bh, sacc[a][kt], 0, 0, 0);
                    sacc[a][kt] = __builtin_amdgcn_mfma_f32_16x16x32_bf16(tHr[a][kc], bl, sacc[a][kt], 0, 0, 0);
                    sacc[a][kt] = __builtin_amdgcn_mfma_f32_16x16x32_bf16(tLo[kc & 1][a], bh, sacc[a][kt], 0, 0, 0);
                }
            }
            __builtin_amdgcn_s_setprio(0);
            if (kc < 7) {                        // write phi chunk kc+1 into other half
                const int wh = ((kc + 1) & 1) * 4;
#pragma unroll
                for (int s = 0; s < 2; ++s) {
                    const int row = s * 64 + prow4;
                    *(short8*)&Fh[swz64(row, wh + lslot)] = pfH[(kc + 1) & 1][s];
                    *(short8*)&Fl[swz64(row, wh + lslot)] = pfL[(kc + 1) & 1][s];
                }
            }
            __syncthreads();
        }

        // ---- softmax stage 1: per-wave partial max over 64 keys ----
#pragma unroll
        for (int a = 0; a < 2; ++a)
#pragma unroll
            for (int r = 0; r < 4; ++r) {
                float v = sacc[a][0][r];
#pragma unroll
                for (int kt = 1; kt < 4; ++kt) v = fmaxf(v, sacc[a][kt][r]);
                v = fmaxf(v, __shfl_xor(v, 1, 64));
                v = fmaxf(v, __shfl_xor(v, 2, 64));
                v = fmaxf(v, __shfl_xor(v, 4, 64));
                v = fmaxf(v, __shfl_xor(v, 8, 64));
                if (l15 == 0) Msh[kv][qh * 32 + a * 16 + quad * 4 + r] = v;
            }
        __syncthreads();

        // ---- softmax stage 2: shared m; P + partial l ----
        float alpha[2][4];
#pragma unroll
        for (int a = 0; a < 2; ++a)
#pragma unroll
            for (int r = 0; r < 4; ++r) {
                const int row = qh * 32 + a * 16 + quad * 4 + r;
                const float vm = fmaxf(Msh[0][row], Msh[1][row]);
                const float mo = mrun[a][r];
                const float mn = fmaxf(mo, vm);
                mrun[a][r] = mn;
                alpha[a][r] = __expf(mo - mn);
            }
        float lpart[2][4];
#pragma unroll
        for (int a = 0; a < 2; ++a)
#pragma unroll
            for (int r = 0; r < 4; ++r) lpart[a][r] = 0.f;
#pragma unroll
        for (int a = 0; a < 2; ++a)
#pragma unroll
            for (int kt = 0; kt < 4; ++kt)
#pragma unroll
                for (int r = 0; r < 4; ++r) {
                    const float p = __expf(sacc[a][kt][r] - mrun[a][r]);
                    Pw2[(qh * 32 + a * 16 + quad * 4 + r) * PSTRP + kv * 64 + kt * 16 + l15] = f2bf(p);
                    lpart[a][r] += p;
                }
#pragma unroll
        for (int a = 0; a < 2; ++a)
#pragma unroll
            for (int r = 0; r < 4; ++r) {
                float s = lpart[a][r];
                s += __shfl_xor(s, 1, 64);
                s += __shfl_xor(s, 2, 64);
                s += __shfl_xor(s, 4, 64);
                s += __shfl_xor(s, 8, 64);
                if (l15 == 0) Lsh[kv][qh * 32 + a * 16 + quad * 4 + r] = s;
            }
        if (kv == 0 && l15 == 0) {
#pragma unroll
            for (int a = 0; a < 2; ++a)
#pragma unroll
                for (int r = 0; r < 4; ++r)
                    Aly[qh * 32 + a * 16 + quad * 4 + r] = alpha[a][r];
        }

        // ---- PV phase: square tiling, 4 chunks of 32 keys, half dbuf ----
#pragma unroll
        for (int s = 0; s < 4; ++s)
            pg[0][s] = *(const short8*)&gB[(long)(s * 64 + prow4) * N + m0 + 0 * 32 + lslot * 8];
#pragma unroll
        for (int s = 0; s < 4; ++s)
            *(short8*)&Gs[swz64(s * 64 + prow4, lslot)] = pg[0][s];
#pragma unroll
        for (int s = 0; s < 4; ++s)
            pg[1][s] = *(const short8*)&gB[(long)(s * 64 + prow4) * N + m0 + 1 * 32 + lslot * 8];
        __syncthreads();   // G0 + Pw2 + Lsh + Aly visible

        // lrun update with full-tile l
#pragma unroll
        for (int a = 0; a < 2; ++a)
#pragma unroll
            for (int r = 0; r < 4; ++r) {
                const int row = qh * 32 + a * 16 + quad * 4 + r;
                const float lt = Lsh[0][row] + Lsh[1][row];
                lrun[a][r] = lrun[a][r] * alpha[a][r] + lt;
            }

        float alr[4][4];
#pragma unroll
        for (int g = 0; g < 4; ++g)
#pragma unroll
            for (int r = 0; r < 4; ++r) alr[g][r] = Aly[g * 16 + quad * 4 + r];
        int noresc = 1;
#pragma unroll
        for (int g = 0; g < 4; ++g)
#pragma unroll
            for (int r = 0; r < 4; ++r) noresc &= (alr[g][r] == 1.f);
        if (!__all(noresc)) {
#pragma unroll
            for (int g = 0; g < 4; ++g)
#pragma unroll
                for (int pj = 0; pj < 4; ++pj)
#pragma unroll
                    for (int r = 0; r < 4; ++r) oacc[g * 4 + pj][r] *= alr[g][r];
        }

#pragma unroll
        for (int mc = 0; mc < 4; ++mc) {
            if (mc < 2) {                        // prefetch chunk mc+2 into set mc&1
#pragma unroll
                for (int s = 0; s < 4; ++s)
                    pg[mc & 1][s] = *(const short8*)&gB[(long)(s * 64 + prow4) * N + m0 + (mc + 2) * 32 + lslot * 8];
            }
            const int half = (mc & 1) * 4;
            short8 af[4];
#pragma unroll
            for (int g = 0; g < 4; ++g)
                af[g] = *(const short8*)&Pw2[(g * 16 + l15) * PSTRP + mc * 32 + quad * 8];
            __builtin_amdgcn_s_setprio(1);
#pragma unroll
            for (int pj = 0; pj < 4; ++pj) {
                const short8 bg = *(const short8*)&Gs[swz64(wid * 64 + pj * 16 + l15, half + quad)];
#pragma unroll
                for (int g = 0; g < 4; ++g)
                    oacc[g * 4 + pj] = __builtin_amdgcn_mfma_f32_16x16x32_bf16(af[g], bg, oacc[g * 4 + pj], 0, 0, 0);
            }
            __builtin_amdgcn_s_setprio(0);
            if (mc < 3) {                        // write chunk mc+1 into other half
                const int wh = ((mc + 1) & 1) * 4;
#pragma unroll
                for (int s = 0; s < 4; ++s)
                    *(short8*)&Gs[swz64(s * 64 + prow4, wh + lslot)] = pg[(mc + 1) & 1][s];
                __syncthreads();
            }
        }
    }

    // ---- finalize: publish 1/l, scale, write fp32 partial + (m,l) ----
    if (kv == 0 && l15 == 0) {
#pragma unroll
        for (int a = 0; a < 2; ++a)
#pragma unroll
            for (int r = 0; r < 4; ++r)
                Aly[qh * 32 + a * 16 + quad * 4 + r] = 1.0f / lrun[a][r];
    }
    __syncthreads();
    float liv[4][4];
#pragma unroll
    for (int g = 0; g < 4; ++g)
#pragma unroll
        for (int r = 0; r < 4; ++r) liv[g][r] = Aly[g * 16 + quad * 4 + r];
#pragma unroll
    for (int g = 0; g < 4; ++g)
#pragma unroll
        for (int pj = 0; pj < 4; ++pj)
#pragma unroll
            for (int r = 0; r < 4; ++r) {
                const int row = q0 + g * 16 + quad * 4 + r;
                const int col = wid * 64 + pj * 16 + l15;
                ypB[(long)row * P + col] = oacc[g * 4 + pj][r] * liv[g][r];
            }
    if (kv == 0 && l15 == 0) {
#pragma unroll
        for (int a = 0; a < 2; ++a)
#pragma unroll
            for (int r = 0; r < 4; ++r) {
                const int row = q0 + qh * 32 + a * 16 + quad * 4 + r;
                mlB[row] = float2{mrun[a][r], lrun[a][r]};
            }
    }
}

// merge the two key-half partials: y = f1*y1 + f2*y2, f_i = l_i e^{m_i-m}/Z
__global__ __launch_bounds__(256) void attn_merge(
    const float* __restrict__ yp, const float2* __restrict__ ml,
    unsigned short* __restrict__ ybf)
{
    const long HALF = 8L * 2048 * 256;
    const long t = (long)blockIdx.x * 256 + threadIdx.x;
    const long row = t >> 5;
    const int  c0  = ((int)t & 31) * 8;
    const float2 a = ml[row];
    const float2 c = ml[8L * 2048 + row];
    const float mx = fmaxf(a.x, c.x);
    const float w1 = a.y * __expf(a.x - mx);
    const float w2 = c.y * __expf(c.x - mx);
    const float inv = 1.0f / (w1 + w2);
    const float f1 = w1 * inv, f2 = w2 * inv;
    const long base = row * 256 + c0;
    const float4 u0 = *(const float4*)&yp[base];
    const float4 u1 = *(const float4*)&yp[base + 4];
    const float4 v0 = *(const float4*)&yp[HALF + base];
    const float4 v1 = *(const float4*)&yp[HALF + base + 4];
    ushort4 o0, o1;
    o0.x = f2bf(f1 * u0.x + f2 * v0.x);
    o0.y = f2bf(f1 * u0.y + f2 * v0.y);
    o0.z = f2bf(f1 * u0.z + f2 * v0.z);
    o0.w = f2bf(f1 * u0.w + f2 * v0.w);
    o1.x = f2bf(f1 * u1.x + f2 * v1.x);
    o1.y = f2bf(f1 * u1.y + f2 * v1.y);
    o1.z = f2bf(f1 * u1.z + f2 * v1.z);
    o1.w = f2bf(f1 * u1.w + f2 * v1.w);
    *(ushort4*)&ybf[base] = o0;
    *(ushort4*)&ybf[base + 4] = o1;
}

// ---------------- BN finalize + apply ----------------
__global__ __launch_bounds__(256) void bn_finalize(
    const float* __restrict__ p1, const float* __restrict__ p2,
    float* __restrict__ mean, float* __restrict__ rstd, float cnt)
{
    const int c = blockIdx.x, t = threadIdx.x;
    __shared__ float rs[256], rq[256];
    rs[t] = p1[(long)c * 256 + t];
    rq[t] = p2[(long)c * 256 + t];
    __syncthreads();
    for (int st = 128; st > 0; st >>= 1) {
        if (t < st) { rs[t] += rs[t + st]; rq[t] += rq[t + st]; }
        __syncthreads();
    }
    if (t == 0) {
        const float m = rs[0] / cnt;
        mean[c] = m;
        rstd[c] = rsqrtf(rq[0] / cnt - m * m + 1e-5f);
    }
}

__global__ __launch_bounds__(256) void bn_apply_bf(
    const unsigned short* __restrict__ z, const float* __restrict__ x,
    const float* __restrict__ mean, const float* __restrict__ rstd,
    const float* __restrict__ gamma, const float* __restrict__ beta,
    float* __restrict__ out, int C, int N)
{
    const long i = ((long)blockIdx.x * 256 + threadIdx.x) * 8;
    const int c = (int)((i / N) % C);
    const float mu = mean[c], rs = rstd[c], ga = gamma[c], be = beta[c];
    const ushort4 z0 = *(const ushort4*)&z[i];
    const ushort4 z1 = *(const ushort4*)&z[i + 4];
    const float4 x0 = *(const float4*)&x[i];
    const float4 x1 = *(const float4*)&x[i + 4];
    float4 o0, o1;
    o0.x = (bf2f(z0.x) - mu) * rs * ga + be + x0.x;
    o0.y = (bf2f(z0.y) - mu) * rs * ga + be + x0.y;
    o0.z = (bf2f(z0.z) - mu) * rs * ga + be + x0.z;
    o0.w = (bf2f(z0.w) - mu) * rs * ga + be + x0.w;
    o1.x = (bf2f(z1.x) - mu) * rs * ga + be + x1.x;
    o1.y = (bf2f(z1.y) - mu) * rs * ga + be + x1.y;
    o1.z = (bf2f(z1.z) - mu) * rs * ga + be + x1.z;
    o1.w = (bf2f(z1.w) - mu) * rs * ga + be + x1.w;
    *(float4*)&out[i] = o0;
    *(float4*)&out[i + 4] = o1;
}

extern "C" void kernel_launch(void* const* d_in, const int* in_sizes, int n_in,
                              void* d_out, int out_size, void* d_ws, size_t ws_size,
                              hipStream_t stream)
{
    const int B = 8, C = 512, N = 2048, P = 256;
    const float* x      = (const float*)d_in[0];
    const float* Wg     = (const float*)d_in[1];
    const float* Wtheta = (const float*)d_in[2];
    const float* Wphi   = (const float*)d_in[3];
    const float* Wz     = (const float*)d_in[4];
    const float* gamma  = (const float*)d_in[5];
    const float* beta   = (const float*)d_in[6];
    float* out = (float*)d_out;

    // ---- workspace layout (float units), same as round 9 ----
    float* ws = (float*)d_ws;
    const long NCle = (long)N * C;            // 1,048,576 per batch (= N*2P)
    const long NP   = (long)N * P;            // 524,288 per batch
    const long R0   = (long)B * NCle;         // 8.39M floats
    unsigned short* xtH   = (unsigned short*)ws;                // B*N*C
    unsigned short* xtL   = xtH + B * NCle;
    unsigned short* zbf   = (unsigned short*)ws;                // aliases xt (dead)
    unsigned short* thphH = (unsigned short*)(ws + R0);         // B*N*2P
    unsigned short* thphL = thphH + B * NCle;                   // B*N*2P
    unsigned short* gbf   = (unsigned short*)(ws + 2 * R0);     // B*P*N
    unsigned short* fbf   = gbf + B * NP;                       // attn partial region
    unsigned short* ybf   = fbf + (long)B * N * N;              // B*N*P
    unsigned short* W2H   = ybf + B * NP;                       // 2P*C
    unsigned short* W2L   = W2H + 2L * P * C;
    unsigned short* WgB   = W2L + 2L * P * C;                   // P*C
    unsigned short* WzB   = WgB + (long)P * C;
    // attn split-K partials in the dead fbf region; ml in dead xtL region.
    float*          yp    = (float*)fbf;                        // [2][B][N][P] fp32
    float2*         ml    = (float2*)(ws + 6L * 1024 * 1024);   // [2][B*N], in xtL
    // BN scratch aliases thph region (dead after fused_attn): [C][256] x2
    float*          bnp1  = ws + R0;
    float*          bnp2  = bnp1 + (long)C * 256;
    float*          mean  = bnp2 + (long)C * 256;
    float*          rstd  = mean + C;

    const long sX = (long)C * N;
    const int  P2 = 2 * P;

    // 1: transpose+split x -> xT hi/lo [B][N][C]
    transpose_split<<<dim3(N / 32, C / 32, B), 256, 0, stream>>>(x, xtH, xtL, C, N);
    // 2: weight preps
    split_w2<<<(2 * P * C + 255) / 256, 256, 0, stream>>>(Wtheta, Wphi, W2H, W2L, P * C);
    cast_bf16<<<P * C / 1024, 256, 0, stream>>>(Wg, WgB);
    cast_bf16<<<P * C / 1024, 256, 0, stream>>>(Wz, WzB);

    // 3: thph [B][N][2P] = xT @ W2^T (split in/out); 128x128, 512 blocks
    mfma_gemm<true, 2, 4, 4><<<dim3(P2 / 128, N / 128, B), 256, 0, stream>>>(
        xtH, xtL, W2H, W2L, thphH, thphL, C, C, C, P2, NCle, 0, NCle, nullptr, nullptr);
    // 4: g [B][P][N] = Wg @ xT^T (plain, bf16 out); 64x128, 512 blocks
    mfma_gemm<false, 1, 2, 4><<<dim3(N / 128, P / 64, B), 256, 0, stream>>>(
        WgB, WgB, xtH, xtH, gbf, gbf, C, C, C, N, 0, NCle, NP, nullptr, nullptr);

    // 5: fused scores+softmax+y, split-K x2 over keys (512 blocks, 2/CU) + merge
    fused_attn<<<dim3(512), 256, 0, stream>>>(thphH, thphL, gbf, yp, ml);
    attn_merge<<<dim3(2048), 256, 0, stream>>>(yp, ml, ybf);

    // 6: z [B][C][N] bf16 = Wz @ yT^T, BN partials (thph dead now)
    mfma_gemm<false, 3, 4, 4><<<dim3(N / 128, C / 128, B), 256, 0, stream>>>(
        WzB, WzB, ybf, ybf, zbf, zbf, P, P, P, N, 0, NP, sX, bnp1, bnp2);

    // 7: BN finalize + apply + residual
    bn_finalize<<<C, 256, 0, stream>>>(bnp1, bnp2, mean, rstd, (float)B * N);
    bn_apply_bf<<<(int)((B * sX) / 2048), 256, 0, stream>>>(zbf, x, mean, rstd, gamma, beta, out, C, N);
}

// Round 8
// 267.077 us; speedup vs baseline: 1.3329x; 1.2647x over previous
//
#include <hip/hip_runtime.h>
#include <hip/hip_bf16.h>

// B=8, C=512, N=2048, P=256.
// Round 18: revert fused_attn to R5 v5.1 (verified best: 100us, 128 VGPR).
// R6/R7 proved the key-split-wave multicast fix can't fit the register
// budget (128-cap -> spill; uncapped -> 216+acc VGPR -> 1 wave/SIMD).
// This round: GEMM3 XCD-locality fix — its 4 col-tiles sharing an A-panel
// had consecutive ids -> 4 different XCDs -> ~4x A re-fetch from HBM.
// Swap grid x<->y (template XYSWAP): same-A blocks now id%8-equal -> same
// XCD -> panel L2-resident. GEMM4/6 already have this property.
// Predicted: fused back to ~100us; GEMM3 45->~33us; total 266.9 -> ~255us.

typedef __attribute__((ext_vector_type(8))) short short8;
typedef __attribute__((ext_vector_type(4))) float floatx4;

// ---------------- bf16 helpers ----------------
__device__ __forceinline__ unsigned short f2bf(float v) {
    __hip_bfloat16 h = __float2bfloat16(v);
    return *(unsigned short*)&h;
}
__device__ __forceinline__ float bf2f(unsigned short u) {
    __hip_bfloat16 h;
    *(unsigned short*)&h = u;
    return __bfloat162float(h);
}

// async global->LDS 16B per lane (dest must be wave-linear: base + lane*16)
__device__ __forceinline__ void gl16(const unsigned short* g, unsigned short* l) {
    __builtin_amdgcn_global_load_lds(
        (const __attribute__((address_space(1))) unsigned int*)g,
        (__attribute__((address_space(3))) unsigned int*)l, 16, 0, 0);
}

// transpose + hi/lo split: X [R][N] fp32 -> Thi/Tlo [N][R] bf16 (batched over z)
__global__ __launch_bounds__(256) void transpose_split(
    const float* __restrict__ X, unsigned short* __restrict__ Thi,
    unsigned short* __restrict__ Tlo, int R, int N)
{
    X   += (long)blockIdx.z * R * N;
    Thi += (long)blockIdx.z * N * R;
    Tlo += (long)blockIdx.z * N * R;
    __shared__ float s[32][33];
    const int tx = threadIdx.x & 31, ty = threadIdx.x >> 5;
    const int n0 = blockIdx.x * 32, r0 = blockIdx.y * 32;
#pragma unroll
    for (int r = 0; r < 4; ++r)
        s[ty + r * 8][tx] = X[(long)(r0 + ty + r * 8) * N + n0 + tx];
    __syncthreads();
#pragma unroll
    for (int r = 0; r < 4; ++r) {
        const int n = ty + r * 8;
        const float v = s[tx][n];
        const unsigned short hi = f2bf(v);
        const unsigned short lo = f2bf(v - bf2f(hi));
        Thi[(long)(n0 + n) * R + r0 + tx] = hi;
        Tlo[(long)(n0 + n) * R + r0 + tx] = lo;
    }
}

// concat [Wth; Wph] rows and hi/lo split: out [2P][C]
__global__ __launch_bounds__(256) void split_w2(
    const float* __restrict__ Wth, const float* __restrict__ Wph,
    unsigned short* __restrict__ Whi, unsigned short* __restrict__ Wlo, int PC)
{
    const int i = blockIdx.x * 256 + threadIdx.x;
    if (i < 2 * PC) {
        const float v = (i < PC) ? Wth[i] : Wph[i - PC];
        const unsigned short hi = f2bf(v);
        Whi[i] = hi;
        Wlo[i] = f2bf(v - bf2f(hi));
    }
}

__global__ __launch_bounds__(256) void cast_bf16(
    const float* __restrict__ X, unsigned short* __restrict__ Y)
{
    const long i = ((long)blockIdx.x * 256 + threadIdx.x) * 4;
    const float4 v = *(const float4*)&X[i];
    ushort4 o;
    o.x = f2bf(v.x); o.y = f2bf(v.y); o.z = f2bf(v.z); o.w = f2bf(v.w);
    *(ushort4*)&Y[i] = o;
}

// ---------------- MFMA GEMM (async global_load_lds, double-buffered) ----------
// C[M][N] = A[M][K] * B[N][K]^T, bf16 K-contiguous inputs, fp32 accum.
// OUTMODE: 0 fp32, 1 bf16, 2 hi/lo split bf16, 3 bf16 + BN partials scratch
//          (slot = (bz*gridDim.x+bx)*2 + (wn>>6); [C][256] scratch).
// XYSWAP: m-tile from blockIdx.x, n-tile from blockIdx.y (XCD locality for
//          blocks sharing an A-panel).
#define BK 32

template <bool SPLIT, int OUTMODE, int FM, int FN, bool XYSWAP>
__global__ __launch_bounds__(256) void mfma_gemm(
    const unsigned short* __restrict__ Ahi, const unsigned short* __restrict__ Alo,
    const unsigned short* __restrict__ Bhi, const unsigned short* __restrict__ Blo,
    void* __restrict__ Cout, void* __restrict__ Cout2,
    int K, int lda, int ldb, int ldc,
    long sA, long sB, long sC,
    float* __restrict__ S1, float* __restrict__ S2)
{
    constexpr int MTM = FM * 32, MTN = FN * 32;
    constexpr int SA = FM / 2, SB = FN / 2;
    constexpr int ASZ = MTM * BK, BSZ = MTN * BK;

    Ahi += (long)blockIdx.z * sA;
    Bhi += (long)blockIdx.z * sB;
    if (SPLIT) { Alo += (long)blockIdx.z * sA; Blo += (long)blockIdx.z * sB; }
    float* Cf = (float*)Cout + (long)blockIdx.z * sC;
    unsigned short* Ch = (unsigned short*)Cout + (long)blockIdx.z * sC;
    unsigned short* Cl = (unsigned short*)Cout2 + (long)blockIdx.z * sC;

    __shared__ unsigned short AsH[2 * ASZ], BsH[2 * BSZ];
    __shared__ unsigned short AsL[SPLIT ? 2 * ASZ : 8], BsL[SPLIT ? 2 * BSZ : 8];

    const int tid = threadIdx.x;
    const int wid = tid >> 6, lane = tid & 63;
    const int wm = (wid >> 1) * (FM * 16), wn = (wid & 1) * (FN * 16);
    const int l15 = lane & 15, quad = lane >> 4;
    const int m0 = (XYSWAP ? blockIdx.x : blockIdx.y) * MTM;
    const int n0 = (XYSWAP ? blockIdx.y : blockIdx.x) * MTN;

    int arow[SA], acol[SA], brow[SB], bcol[SB];
#pragma unroll
    for (int t = 0; t < SA; ++t) {
        const int gid = t * 256 + tid;
        arow[t] = gid >> 2; acol[t] = (gid & 3) * 8;
    }
#pragma unroll
    for (int t = 0; t < SB; ++t) {
        const int gid = t * 256 + tid;
        brow[t] = gid >> 2; bcol[t] = (gid & 3) * 8;
    }

    auto stage = [&](int k0, int buf) {
#pragma unroll
        for (int t = 0; t < SA; ++t) {
            const long o = (long)(m0 + arow[t]) * lda + k0 + acol[t];
            const int d = buf * ASZ + (t * 256 + tid) * 8;
            gl16(&Ahi[o], &AsH[d]);
            if (SPLIT) gl16(&Alo[o], &AsL[d]);
        }
#pragma unroll
        for (int t = 0; t < SB; ++t) {
            const long o = (long)(n0 + brow[t]) * ldb + k0 + bcol[t];
            const int d = buf * BSZ + (t * 256 + tid) * 8;
            gl16(&Bhi[o], &BsH[d]);
            if (SPLIT) gl16(&Blo[o], &BsL[d]);
        }
    };

    floatx4 acc[FM][FN];
#pragma unroll
    for (int i = 0; i < FM; ++i)
#pragma unroll
        for (int j = 0; j < FN; ++j) acc[i][j] = (floatx4){0.f, 0.f, 0.f, 0.f};

    const int iters = K / BK;
    stage(0, 0);
    __syncthreads();

    for (int it = 0; it < iters; ++it) {
        const int cur = it & 1;
        if (it + 1 < iters) stage((it + 1) * BK, cur ^ 1);

        short8 ah[FM], bh[FN], al[SPLIT ? FM : 1], bl[SPLIT ? FN : 1];
#pragma unroll
        for (int i = 0; i < FM; ++i) {
            ah[i] = *(const short8*)&AsH[cur * ASZ + (wm + i * 16 + l15) * BK + quad * 8];
            if (SPLIT) al[i] = *(const short8*)&AsL[cur * ASZ + (wm + i * 16 + l15) * BK + quad * 8];
        }
#pragma unroll
        for (int j = 0; j < FN; ++j) {
            bh[j] = *(const short8*)&BsH[cur * BSZ + (wn + j * 16 + l15) * BK + quad * 8];
            if (SPLIT) bl[j] = *(const short8*)&BsL[cur * BSZ + (wn + j * 16 + l15) * BK + quad * 8];
        }
#pragma unroll
        for (int i = 0; i < FM; ++i)
#pragma unroll
            for (int j = 0; j < FN; ++j) {
                acc[i][j] = __builtin_amdgcn_mfma_f32_16x16x32_bf16(ah[i], bh[j], acc[i][j], 0, 0, 0);
                if (SPLIT) {
                    acc[i][j] = __builtin_amdgcn_mfma_f32_16x16x32_bf16(ah[i], bl[j], acc[i][j], 0, 0, 0);
                    acc[i][j] = __builtin_amdgcn_mfma_f32_16x16x32_bf16(al[i], bh[j], acc[i][j], 0, 0, 0);
                }
            }

        __syncthreads();
    }

#pragma unroll
    for (int i = 0; i < FM; ++i)
#pragma unroll
        for (int j = 0; j < FN; ++j) {
            const int m = m0 + wm + i * 16 + quad * 4;
            const int n = n0 + wn + j * 16 + l15;
#pragma unroll
            for (int r = 0; r < 4; ++r) {
                const float v = acc[i][j][r];
                const long idx = (long)(m + r) * ldc + n;
                if (OUTMODE == 0) {
                    Cf[idx] = v;
                } else if (OUTMODE == 1 || OUTMODE == 3) {
                    Ch[idx] = f2bf(v);
                } else {
                    const unsigned short hi = f2bf(v);
                    Ch[idx] = hi;
                    Cl[idx] = f2bf(v - bf2f(hi));
                }
            }
        }

    if (OUTMODE == 3) {
        const int slot = (blockIdx.z * gridDim.x + blockIdx.x) * 2 + (wn >> 6);
#pragma unroll
        for (int i = 0; i < FM; ++i)
#pragma unroll
            for (int r = 0; r < 4; ++r) {
                float s = 0.f, q = 0.f;
#pragma unroll
                for (int j = 0; j < FN; ++j) {
                    const float v = acc[i][j][r];
                    s += v; q += v * v;
                }
#pragma unroll
                for (int msk = 1; msk < 16; msk <<= 1) {
                    s += __shfl_xor(s, msk, 64);
                    q += __shfl_xor(q, msk, 64);
                }
                if (l15 == 0) {
                    const int row = m0 + wm + i * 16 + quad * 4 + r;
                    S1[(long)row * 256 + slot] = s;
                    S2[(long)row * 256 + slot] = q;
                }
            }
    }
}

// ---------------- fused scores+softmax+y v5.1 (R5 verified best) ----------------
// 512 blocks (b = id&7, kh = (id>>3)&1, qt = id>>4), 4 waves.
// S phase: 8 chunks of 32 c; chunk kc lives in column-half kc&1 of the
//   [128][64]+swz64 phi tile; per chunk {gload kc+2 | MFMA kc | write kc+1}
//   then ONE barrier. PV: square tiling (64q x 64p/wave), 4 chunks of 32 keys.
// LDS: FG 32,768B (aliased phi/G) + Pw 17,408B + Aly 256B = 50,432B.
#define PSTRP 136   // P LDS row stride (128 keys + 8 pad)

// swizzled short-offset into a [rows][64-short] tile: 16B slot ^= row&7
__device__ __forceinline__ int swz64(int row, int slot) {
    return (row << 6) + (((slot ^ row) & 7) << 3);
}

__global__ __launch_bounds__(256, 2) void fused_attn(
    const unsigned short* __restrict__ thphH,
    const unsigned short* __restrict__ thphL,
    const unsigned short* __restrict__ gbf,
    float* __restrict__ yp,       // [2][B][N][P] fp32 partials (self-normalized)
    float2* __restrict__ ml)      // [2][B*N] {m, l}
{
    const int N = 2048, P = 256, P2 = 512;
    const int id = blockIdx.x;
    const int b  = id & 7;            // XCD-locality heuristic
    const int kh = (id >> 3) & 1;     // key half
    const int qt = id >> 4;           // 0..31
    const int q0 = qt * 64;

    const unsigned short* thB = thphH + (long)b * N * P2;
    const unsigned short* tlB = thphL + (long)b * N * P2;
    const unsigned short* gB  = gbf   + (long)b * P * N;
    float*  ypB = yp + (long)kh * (8L * N * P) + (long)b * N * P;
    float2* mlB = ml + (long)kh * (8L * N) + (long)b * N;

    // phi hi/lo and G share the same LDS (disjoint phases / halves, fenced)
    __shared__ unsigned short FG[2 * 128 * 64];       // 16,384 shorts = 32,768 B
    unsigned short* Fh = FG;                          // [128][64] swizzled
    unsigned short* Fl = FG + 128 * 64;
    unsigned short* Gs = FG;                          // [256][64] swizzled
    __shared__ unsigned short Pw[4][16 * PSTRP];      // per-rowgroup P (shared)
    __shared__ float Aly[64];                         // per-row alpha / linv

    const int tid = threadIdx.x;
    const int wid = tid >> 6, lane = tid & 63;
    const int l15 = lane & 15, quad = lane >> 4;

    // theta fragments in registers: wave rows [q0+wid*16, +16), A m = l15
    short8 tHr[8], tLr[8];
    {
        const unsigned short* t1 = thB + (long)(q0 + wid * 16 + l15) * P2;
        const unsigned short* t2 = tlB + (long)(q0 + wid * 16 + l15) * P2;
#pragma unroll
        for (int kt = 0; kt < 8; ++kt) {
            tHr[kt] = *(const short8*)&t1[kt * 32 + quad * 8];
            tLr[kt] = *(const short8*)&t2[kt * 32 + quad * 8];
        }
    }

    float mrun[4], lrun[4];
#pragma unroll
    for (int r = 0; r < 4; ++r) { mrun[r] = -1e30f; lrun[r] = 0.f; }

    // oacc[g*4+pj]: rows g*16+quad*4+r, cols wid*64+pj*16+l15
    floatx4 oacc[16];
#pragma unroll
    for (int p = 0; p < 16; ++p) oacc[p] = (floatx4){0.f, 0.f, 0.f, 0.f};

    // staging: prow4 = tid>>2 (0..63), lslot = tid&3 (16B granule in 32-short half)
    const int prow4 = tid >> 2, lslot = tid & 3;
    short8 pfH[2][2], pfL[2][2];   // [set][s], set = chunk&1 (static under unroll)
    short8 pg[2][4];

    for (int mt = 0; mt < 8; ++mt) {
        const int m0 = kh * 1024 + mt * 128;

        // ---- S phase: 8 chunks of 32 c, half-column dbuf ----
        floatx4 sacc[8];
#pragma unroll
        for (int j = 0; j < 8; ++j) sacc[j] = (floatx4){0.f, 0.f, 0.f, 0.f};

        // prologue: chunk0 -> half0, prefetch chunk1.
#pragma unroll
        for (int s = 0; s < 2; ++s) {
            const long o = (long)(m0 + s * 64 + prow4) * P2 + P + 0 * 32 + lslot * 8;
            pfH[0][s] = *(const short8*)&thB[o];
            pfL[0][s] = *(const short8*)&tlB[o];
        }
#pragma unroll
        for (int s = 0; s < 2; ++s) {
            const int row = s * 64 + prow4;
            *(short8*)&Fh[swz64(row, lslot)] = pfH[0][s];
            *(short8*)&Fl[swz64(row, lslot)] = pfL[0][s];
        }
#pragma unroll
        for (int s = 0; s < 2; ++s) {
            const long o = (long)(m0 + s * 64 + prow4) * P2 + P + 1 * 32 + lslot * 8;
            pfH[1][s] = *(const short8*)&thB[o];
            pfL[1][s] = *(const short8*)&tlB[o];
        }
        __syncthreads();

#pragma unroll
        for (int kc = 0; kc < 8; ++kc) {
            if (kc < 6) {                        // prefetch chunk kc+2 into set kc&1
#pragma unroll
                for (int s = 0; s < 2; ++s) {
                    const long o = (long)(m0 + s * 64 + prow4) * P2 + P + (kc + 2) * 32 + lslot * 8;
                    pfH[kc & 1][s] = *(const short8*)&thB[o];
                    pfL[kc & 1][s] = *(const short8*)&tlB[o];
                }
            }
            const short8 aH = tHr[kc];
            const short8 aL = tLr[kc];
            const int half = (kc & 1) * 4;
            __builtin_amdgcn_s_setprio(1);
#pragma unroll
            for (int j = 0; j < 8; ++j) {
                const int ro = swz64(j * 16 + l15, half + quad);
                const short8 bh = *(const short8*)&Fh[ro];
                const short8 bl = *(const short8*)&Fl[ro];
                sacc[j] = __builtin_amdgcn_mfma_f32_16x16x32_bf16(aH, bh, sacc[j], 0, 0, 0);
                sacc[j] = __builtin_amdgcn_mfma_f32_16x16x32_bf16(aH, bl, sacc[j], 0, 0, 0);
                sacc[j] = __builtin_amdgcn_mfma_f32_16x16x32_bf16(aL, bh, sacc[j], 0, 0, 0);
            }
            __builtin_amdgcn_s_setprio(0);
            if (kc < 7) {                        // write chunk kc+1 into other half
                const int wh = ((kc + 1) & 1) * 4;
#pragma unroll
                for (int s = 0; s < 2; ++s) {
                    const int row = s * 64 + prow4;
                    *(short8*)&Fh[swz64(row, wh + lslot)] = pfH[(kc + 1) & 1][s];
                    *(short8*)&Fl[swz64(row, wh + lslot)] = pfL[(kc + 1) & 1][s];
                }
            }
            __syncthreads();
        }

        // ---- online softmax (registers only; rows = quad*4+r) ----
        float alpha[4];
#pragma unroll
        for (int r = 0; r < 4; ++r) {
            float v = sacc[0][r];
#pragma unroll
            for (int j = 1; j < 8; ++j) v = fmaxf(v, sacc[j][r]);
            v = fmaxf(v, __shfl_xor(v, 1, 64));
            v = fmaxf(v, __shfl_xor(v, 2, 64));
            v = fmaxf(v, __shfl_xor(v, 4, 64));
            v = fmaxf(v, __shfl_xor(v, 8, 64));
            const float mo = mrun[r];
            const float mn = fmaxf(mo, v);
            mrun[r] = mn;
            alpha[r] = __expf(mo - mn);
        }
        float lpart[4] = {0.f, 0.f, 0.f, 0.f};
#pragma unroll
        for (int j = 0; j < 8; ++j)
#pragma unroll
            for (int r = 0; r < 4; ++r) {
                const float p = __expf(sacc[j][r] - mrun[r]);
                Pw[wid][(quad * 4 + r) * PSTRP + j * 16 + l15] = f2bf(p);
                lpart[r] += p;
            }
#pragma unroll
        for (int r = 0; r < 4; ++r) {
            float s = lpart[r];
            s += __shfl_xor(s, 1, 64);
            s += __shfl_xor(s, 2, 64);
            s += __shfl_xor(s, 4, 64);
            s += __shfl_xor(s, 8, 64);
            lrun[r] = lrun[r] * alpha[r] + s;
        }
        if (l15 == 0) {                    // publish row alphas for PV rescale
#pragma unroll
            for (int r = 0; r < 4; ++r) Aly[wid * 16 + quad * 4 + r] = alpha[r];
        }

        // ---- PV phase: square tiling, 4 chunks of 32 keys, half dbuf ----
#pragma unroll
        for (int s = 0; s < 4; ++s)
            pg[0][s] = *(const short8*)&gB[(long)(s * 64 + prow4) * N + m0 + 0 * 32 + lslot * 8];
#pragma unroll
        for (int s = 0; s < 4; ++s)
            *(short8*)&Gs[swz64(s * 64 + prow4, lslot)] = pg[0][s];
#pragma unroll
        for (int s = 0; s < 4; ++s)
            pg[1][s] = *(const short8*)&gB[(long)(s * 64 + prow4) * N + m0 + 1 * 32 + lslot * 8];
        __syncthreads();   // G0 + Pw + Aly visible

        float alr[4][4];
#pragma unroll
        for (int g = 0; g < 4; ++g)
#pragma unroll
            for (int r = 0; r < 4; ++r) alr[g][r] = Aly[g * 16 + quad * 4 + r];
        int noresc = 1;
#pragma unroll
        for (int g = 0; g < 4; ++g)
#pragma unroll
            for (int r = 0; r < 4; ++r) noresc &= (alr[g][r] == 1.f);
        if (!__all(noresc)) {
#pragma unroll
            for (int g = 0; g < 4; ++g)
#pragma unroll
                for (int pj = 0; pj < 4; ++pj)
#pragma unroll
                    for (int r = 0; r < 4; ++r) oacc[g * 4 + pj][r] *= alr[g][r];
        }

#pragma unroll
        for (int mc = 0; mc < 4; ++mc) {
            if (mc < 2) {                        // prefetch chunk mc+2 into set mc&1
#pragma unroll
                for (int s = 0; s < 4; ++s)
                    pg[mc & 1][s] = *(const short8*)&gB[(long)(s * 64 + prow4) * N + m0 + (mc + 2) * 32 + lslot * 8];
            }
            const int half = (mc & 1) * 4;
            short8 af[4];
#pragma unroll
            for (int g = 0; g < 4; ++g)
                af[g] = *(const short8*)&Pw[g][l15 * PSTRP + mc * 32 + quad * 8];
            __builtin_amdgcn_s_setprio(1);
#pragma unroll
            for (int pj = 0; pj < 4; ++pj) {
                const short8 bg = *(const short8*)&Gs[swz64(wid * 64 + pj * 16 + l15, half + quad)];
#pragma unroll
                for (int g = 0; g < 4; ++g)
                    oacc[g * 4 + pj] = __builtin_amdgcn_mfma_f32_16x16x32_bf16(af[g], bg, oacc[g * 4 + pj], 0, 0, 0);
            }
            __builtin_amdgcn_s_setprio(0);
            if (mc < 3) {                        // write chunk mc+1 into other half
                const int wh = ((mc + 1) & 1) * 4;
#pragma unroll
                for (int s = 0; s < 4; ++s)
                    *(short8*)&Gs[swz64(s * 64 + prow4, wh + lslot)] = pg[(mc + 1) & 1][s];
                __syncthreads();
            }
        }
    }

    // ---- finalize: publish 1/l, scale, write fp32 partial + (m,l) ----
    if (l15 == 0) {
#pragma unroll
        for (int r = 0; r < 4; ++r) Aly[wid * 16 + quad * 4 + r] = 1.0f / lrun[r];
    }
    __syncthreads();
    float liv[4][4];
#pragma unroll
    for (int g = 0; g < 4; ++g)
#pragma unroll
        for (int r = 0; r < 4; ++r) liv[g][r] = Aly[g * 16 + quad * 4 + r];
#pragma unroll
    for (int g = 0; g < 4; ++g)
#pragma unroll
        for (int pj = 0; pj < 4; ++pj)
#pragma unroll
            for (int r = 0; r < 4; ++r) {
                const int row = q0 + g * 16 + quad * 4 + r;
                const int col = wid * 64 + pj * 16 + l15;
                ypB[(long)row * P + col] = oacc[g * 4 + pj][r] * liv[g][r];
            }
    if (l15 == 0) {
#pragma unroll
        for (int r = 0; r < 4; ++r) {
            const int row = q0 + wid * 16 + quad * 4 + r;
            mlB[row] = float2{mrun[r], lrun[r]};
        }
    }
}

// merge the two key-half partials: y = f1*y1 + f2*y2, f_i = l_i e^{m_i-m}/Z
__global__ __launch_bounds__(256) void attn_merge(
    const float* __restrict__ yp, const float2* __restrict__ ml,
    unsigned short* __restrict__ ybf)
{
    const long HALF = 8L * 2048 * 256;
    const long t = (long)blockIdx.x * 256 + threadIdx.x;
    const long row = t >> 5;
    const int  c0  = ((int)t & 31) * 8;
    const float2 a = ml[row];
    const float2 c = ml[8L * 2048 + row];
    const float mx = fmaxf(a.x, c.x);
    const float w1 = a.y * __expf(a.x - mx);
    const float w2 = c.y * __expf(c.x - mx);
    const float inv = 1.0f / (w1 + w2);
    const float f1 = w1 * inv, f2 = w2 * inv;
    const long base = row * 256 + c0;
    const float4 u0 = *(const float4*)&yp[base];
    const float4 u1 = *(const float4*)&yp[base + 4];
    const float4 v0 = *(const float4*)&yp[HALF + base];
    const float4 v1 = *(const float4*)&yp[HALF + base + 4];
    ushort4 o0, o1;
    o0.x = f2bf(f1 * u0.x + f2 * v0.x);
    o0.y = f2bf(f1 * u0.y + f2 * v0.y);
    o0.z = f2bf(f1 * u0.z + f2 * v0.z);
    o0.w = f2bf(f1 * u0.w + f2 * v0.w);
    o1.x = f2bf(f1 * u1.x + f2 * v1.x);
    o1.y = f2bf(f1 * u1.y + f2 * v1.y);
    o1.z = f2bf(f1 * u1.z + f2 * v1.z);
    o1.w = f2bf(f1 * u1.w + f2 * v1.w);
    *(ushort4*)&ybf[base] = o0;
    *(ushort4*)&ybf[base + 4] = o1;
}

// ---------------- BN finalize + apply ----------------
__global__ __launch_bounds__(256) void bn_finalize(
    const float* __restrict__ p1, const float* __restrict__ p2,
    float* __restrict__ mean, float* __restrict__ rstd, float cnt)
{
    const int c = blockIdx.x, t = threadIdx.x;
    __shared__ float rs[256], rq[256];
    rs[t] = p1[(long)c * 256 + t];
    rq[t] = p2[(long)c * 256 + t];
    __syncthreads();
    for (int st = 128; st > 0; st >>= 1) {
        if (t < st) { rs[t] += rs[t + st]; rq[t] += rq[t + st]; }
        __syncthreads();
    }
    if (t == 0) {
        const float m = rs[0] / cnt;
        mean[c] = m;
        rstd[c] = rsqrtf(rq[0] / cnt - m * m + 1e-5f);
    }
}

__global__ __launch_bounds__(256) void bn_apply_bf(
    const unsigned short* __restrict__ z, const float* __restrict__ x,
    const float* __restrict__ mean, const float* __restrict__ rstd,
    const float* __restrict__ gamma, const float* __restrict__ beta,
    float* __restrict__ out, int C, int N)
{
    const long i = ((long)blockIdx.x * 256 + threadIdx.x) * 8;
    const int c = (int)((i / N) % C);
    const float mu = mean[c], rs = rstd[c], ga = gamma[c], be = beta[c];
    const ushort4 z0 = *(const ushort4*)&z[i];
    const ushort4 z1 = *(const ushort4*)&z[i + 4];
    const float4 x0 = *(const float4*)&x[i];
    const float4 x1 = *(const float4*)&x[i + 4];
    float4 o0, o1;
    o0.x = (bf2f(z0.x) - mu) * rs * ga + be + x0.x;
    o0.y = (bf2f(z0.y) - mu) * rs * ga + be + x0.y;
    o0.z = (bf2f(z0.z) - mu) * rs * ga + be + x0.z;
    o0.w = (bf2f(z0.w) - mu) * rs * ga + be + x0.w;
    o1.x = (bf2f(z1.x) - mu) * rs * ga + be + x1.x;
    o1.y = (bf2f(z1.y) - mu) * rs * ga + be + x1.y;
    o1.z = (bf2f(z1.z) - mu) * rs * ga + be + x1.z;
    o1.w = (bf2f(z1.w) - mu) * rs * ga + be + x1.w;
    *(float4*)&out[i] = o0;
    *(float4*)&out[i + 4] = o1;
}

extern "C" void kernel_launch(void* const* d_in, const int* in_sizes, int n_in,
                              void* d_out, int out_size, void* d_ws, size_t ws_size,
                              hipStream_t stream)
{
    const int B = 8, C = 512, N = 2048, P = 256;
    const float* x      = (const float*)d_in[0];
    const float* Wg     = (const float*)d_in[1];
    const float* Wtheta = (const float*)d_in[2];
    const float* Wphi   = (const float*)d_in[3];
    const float* Wz     = (const float*)d_in[4];
    const float* gamma  = (const float*)d_in[5];
    const float* beta   = (const float*)d_in[6];
    float* out = (float*)d_out;

    // ---- workspace layout (float units), same as round 9 ----
    float* ws = (float*)d_ws;
    const long NCle = (long)N * C;            // 1,048,576 per batch (= N*2P)
    const long NP   = (long)N * P;            // 524,288 per batch
    const long R0   = (long)B * NCle;         // 8.39M floats
    unsigned short* xtH   = (unsigned short*)ws;                // B*N*C
    unsigned short* xtL   = xtH + B * NCle;
    unsigned short* zbf   = (unsigned short*)ws;                // aliases xt (dead)
    unsigned short* thphH = (unsigned short*)(ws + R0);         // B*N*2P
    unsigned short* thphL = thphH + B * NCle;                   // B*N*2P
    unsigned short* gbf   = (unsigned short*)(ws + 2 * R0);     // B*P*N
    unsigned short* fbf   = gbf + B * NP;                       // attn partial region
    unsigned short* ybf   = fbf + (long)B * N * N;              // B*N*P
    unsigned short* W2H   = ybf + B * NP;                       // 2P*C
    unsigned short* W2L   = W2H + 2L * P * C;
    unsigned short* WgB   = W2L + 2L * P * C;                   // P*C
    unsigned short* WzB   = WgB + (long)P * C;
    // attn split-K partials in the dead fbf region; ml in dead xtL region.
    float*          yp    = (float*)fbf;                        // [2][B][N][P] fp32
    float2*         ml    = (float2*)(ws + 6L * 1024 * 1024);   // [2][B*N], in xtL
    // BN scratch aliases thph region (dead after fused_attn): [C][256] x2
    float*          bnp1  = ws + R0;
    float*          bnp2  = bnp1 + (long)C * 256;
    float*          mean  = bnp2 + (long)C * 256;
    float*          rstd  = mean + C;

    const long sX = (long)C * N;
    const int  P2 = 2 * P;

    // 1: transpose+split x -> xT hi/lo [B][N][C]
    transpose_split<<<dim3(N / 32, C / 32, B), 256, 0, stream>>>(x, xtH, xtL, C, N);
    // 2: weight preps
    split_w2<<<(2 * P * C + 255) / 256, 256, 0, stream>>>(Wtheta, Wphi, W2H, W2L, P * C);
    cast_bf16<<<P * C / 1024, 256, 0, stream>>>(Wg, WgB);
    cast_bf16<<<P * C / 1024, 256, 0, stream>>>(Wz, WzB);

    // 3: thph [B][N][2P] = xT @ W2^T (split in/out); XYSWAP grid: blocks
    //    sharing an A-panel (4 col-tiles) now id%8-equal -> same XCD L2.
    mfma_gemm<true, 2, 4, 4, true><<<dim3(N / 128, P2 / 128, B), 256, 0, stream>>>(
        xtH, xtL, W2H, W2L, thphH, thphL, C, C, C, P2, NCle, 0, NCle, nullptr, nullptr);
    // 4: g [B][P][N] = Wg @ xT^T (plain, bf16 out); 64x128, 512 blocks
    mfma_gemm<false, 1, 2, 4, false><<<dim3(N / 128, P / 64, B), 256, 0, stream>>>(
        WgB, WgB, xtH, xtH, gbf, gbf, C, C, C, N, 0, NCle, NP, nullptr, nullptr);

    // 5: fused scores+softmax+y, split-K x2 over keys (512 blocks, 2/CU) + merge
    fused_attn<<<dim3(512), 256, 0, stream>>>(thphH, thphL, gbf, yp, ml);
    attn_merge<<<dim3(2048), 256, 0, stream>>>(yp, ml, ybf);

    // 6: z [B][C][N] bf16 = Wz @ yT^T, BN partials (thph dead now)
    mfma_gemm<false, 3, 4, 4, false><<<dim3(N / 128, C / 128, B), 256, 0, stream>>>(
        WzB, WzB, ybf, ybf, zbf, zbf, P, P, P, N, 0, NP, sX, bnp1, bnp2);

    // 7: BN finalize + apply + residual
    bn_finalize<<<C, 256, 0, stream>>>(bnp1, bnp2, mean, rstd, (float)B * N);
    bn_apply_bf<<<(int)((B * sX) / 2048), 256, 0, stream>>>(zbf, x, mean, rstd, gamma, beta, out, C, N);
}

// Round 9
// 265.623 us; speedup vs baseline: 1.3402x; 1.0055x over previous
//
#include <hip/hip_runtime.h>
#include <hip/hip_bf16.h>

// B=8, C=512, N=2048, P=256.
// Round 19: memory-bound cleanup. fused_attn untouched (verified local opt,
// 100us). transpose_split rewritten: float4 loads (16B/lane), LDS [32][133]
// (stride-133 -> conflict-free column reads), short8 16B stores both planes
// (was 4B loads / 2B stores on a ~100MB kernel). bn_apply: hardcoded
// shift/mask for (i/N)%C (was runtime int division).
// Predicted: transpose ~25 -> ~13us, bn_apply -1-2us, total 267 -> ~255us.
// fused_attn counters unchanged (100us, VGPR 128, FETCH 20.5MB).

typedef __attribute__((ext_vector_type(8))) short short8;
typedef __attribute__((ext_vector_type(4))) float floatx4;

// ---------------- bf16 helpers ----------------
__device__ __forceinline__ unsigned short f2bf(float v) {
    __hip_bfloat16 h = __float2bfloat16(v);
    return *(unsigned short*)&h;
}
__device__ __forceinline__ float bf2f(unsigned short u) {
    __hip_bfloat16 h;
    *(unsigned short*)&h = u;
    return __bfloat162float(h);
}

// async global->LDS 16B per lane (dest must be wave-linear: base + lane*16)
__device__ __forceinline__ void gl16(const unsigned short* g, unsigned short* l) {
    __builtin_amdgcn_global_load_lds(
        (const __attribute__((address_space(1))) unsigned int*)g,
        (__attribute__((address_space(3))) unsigned int*)l, 16, 0, 0);
}

// transpose + hi/lo split: X [R][N] fp32 -> Thi/Tlo [N][R] bf16 (batched over z)
// v2: 32r x 128n macro-tile, float4 loads, conflict-free LDS, short8 stores.
__global__ __launch_bounds__(256) void transpose_split(
    const float* __restrict__ X, unsigned short* __restrict__ Thi,
    unsigned short* __restrict__ Tlo, int R, int N)
{
    X   += (long)blockIdx.z * R * N;
    Thi += (long)blockIdx.z * N * R;
    Tlo += (long)blockIdx.z * N * R;
    __shared__ float s[32][133];      // stride 133: gcd(133,32)=1 -> conflict-free cols
    const int t = threadIdx.x;
    const int n0 = blockIdx.x * 128, r0 = blockIdx.y * 32;
    const int nf = (t & 31) * 4, rf = t >> 5;
#pragma unroll
    for (int rr = 0; rr < 4; ++rr) {
        const int row = rf + rr * 8;
        const float4 v = *(const float4*)&X[(long)(r0 + row) * N + n0 + nf];
        s[row][nf]     = v.x;
        s[row][nf + 1] = v.y;
        s[row][nf + 2] = v.z;
        s[row][nf + 3] = v.w;
    }
    __syncthreads();
    const int n = t >> 1, rs = (t & 1) * 16;
    short8 h0, h1, l0, l1;
#pragma unroll
    for (int j = 0; j < 8; ++j) {
        const float v = s[rs + j][n];
        const unsigned short h = f2bf(v);
        h0[j] = (short)h;
        l0[j] = (short)f2bf(v - bf2f(h));
    }
#pragma unroll
    for (int j = 0; j < 8; ++j) {
        const float v = s[rs + 8 + j][n];
        const unsigned short h = f2bf(v);
        h1[j] = (short)h;
        l1[j] = (short)f2bf(v - bf2f(h));
    }
    const long ob = (long)(n0 + n) * R + r0 + rs;
    *(short8*)&Thi[ob]     = h0;
    *(short8*)&Thi[ob + 8] = h1;
    *(short8*)&Tlo[ob]     = l0;
    *(short8*)&Tlo[ob + 8] = l1;
}

// concat [Wth; Wph] rows and hi/lo split: out [2P][C]
__global__ __launch_bounds__(256) void split_w2(
    const float* __restrict__ Wth, const float* __restrict__ Wph,
    unsigned short* __restrict__ Whi, unsigned short* __restrict__ Wlo, int PC)
{
    const int i = blockIdx.x * 256 + threadIdx.x;
    if (i < 2 * PC) {
        const float v = (i < PC) ? Wth[i] : Wph[i - PC];
        const unsigned short hi = f2bf(v);
        Whi[i] = hi;
        Wlo[i] = f2bf(v - bf2f(hi));
    }
}

__global__ __launch_bounds__(256) void cast_bf16(
    const float* __restrict__ X, unsigned short* __restrict__ Y)
{
    const long i = ((long)blockIdx.x * 256 + threadIdx.x) * 4;
    const float4 v = *(const float4*)&X[i];
    ushort4 o;
    o.x = f2bf(v.x); o.y = f2bf(v.y); o.z = f2bf(v.z); o.w = f2bf(v.w);
    *(ushort4*)&Y[i] = o;
}

// ---------------- MFMA GEMM (async global_load_lds, double-buffered) ----------
// C[M][N] = A[M][K] * B[N][K]^T, bf16 K-contiguous inputs, fp32 accum.
// OUTMODE: 0 fp32, 1 bf16, 2 hi/lo split bf16, 3 bf16 + BN partials scratch
//          (slot = (bz*gridDim.x+bx)*2 + (wn>>6); [C][256] scratch).
// XYSWAP: m-tile from blockIdx.x, n-tile from blockIdx.y.
#define BK 32

template <bool SPLIT, int OUTMODE, int FM, int FN, bool XYSWAP>
__global__ __launch_bounds__(256) void mfma_gemm(
    const unsigned short* __restrict__ Ahi, const unsigned short* __restrict__ Alo,
    const unsigned short* __restrict__ Bhi, const unsigned short* __restrict__ Blo,
    void* __restrict__ Cout, void* __restrict__ Cout2,
    int K, int lda, int ldb, int ldc,
    long sA, long sB, long sC,
    float* __restrict__ S1, float* __restrict__ S2)
{
    constexpr int MTM = FM * 32, MTN = FN * 32;
    constexpr int SA = FM / 2, SB = FN / 2;
    constexpr int ASZ = MTM * BK, BSZ = MTN * BK;

    Ahi += (long)blockIdx.z * sA;
    Bhi += (long)blockIdx.z * sB;
    if (SPLIT) { Alo += (long)blockIdx.z * sA; Blo += (long)blockIdx.z * sB; }
    float* Cf = (float*)Cout + (long)blockIdx.z * sC;
    unsigned short* Ch = (unsigned short*)Cout + (long)blockIdx.z * sC;
    unsigned short* Cl = (unsigned short*)Cout2 + (long)blockIdx.z * sC;

    __shared__ unsigned short AsH[2 * ASZ], BsH[2 * BSZ];
    __shared__ unsigned short AsL[SPLIT ? 2 * ASZ : 8], BsL[SPLIT ? 2 * BSZ : 8];

    const int tid = threadIdx.x;
    const int wid = tid >> 6, lane = tid & 63;
    const int wm = (wid >> 1) * (FM * 16), wn = (wid & 1) * (FN * 16);
    const int l15 = lane & 15, quad = lane >> 4;
    const int m0 = (XYSWAP ? blockIdx.x : blockIdx.y) * MTM;
    const int n0 = (XYSWAP ? blockIdx.y : blockIdx.x) * MTN;

    int arow[SA], acol[SA], brow[SB], bcol[SB];
#pragma unroll
    for (int t = 0; t < SA; ++t) {
        const int gid = t * 256 + tid;
        arow[t] = gid >> 2; acol[t] = (gid & 3) * 8;
    }
#pragma unroll
    for (int t = 0; t < SB; ++t) {
        const int gid = t * 256 + tid;
        brow[t] = gid >> 2; bcol[t] = (gid & 3) * 8;
    }

    auto stage = [&](int k0, int buf) {
#pragma unroll
        for (int t = 0; t < SA; ++t) {
            const long o = (long)(m0 + arow[t]) * lda + k0 + acol[t];
            const int d = buf * ASZ + (t * 256 + tid) * 8;
            gl16(&Ahi[o], &AsH[d]);
            if (SPLIT) gl16(&Alo[o], &AsL[d]);
        }
#pragma unroll
        for (int t = 0; t < SB; ++t) {
            const long o = (long)(n0 + brow[t]) * ldb + k0 + bcol[t];
            const int d = buf * BSZ + (t * 256 + tid) * 8;
            gl16(&Bhi[o], &BsH[d]);
            if (SPLIT) gl16(&Blo[o], &BsL[d]);
        }
    };

    floatx4 acc[FM][FN];
#pragma unroll
    for (int i = 0; i < FM; ++i)
#pragma unroll
        for (int j = 0; j < FN; ++j) acc[i][j] = (floatx4){0.f, 0.f, 0.f, 0.f};

    const int iters = K / BK;
    stage(0, 0);
    __syncthreads();

    for (int it = 0; it < iters; ++it) {
        const int cur = it & 1;
        if (it + 1 < iters) stage((it + 1) * BK, cur ^ 1);

        short8 ah[FM], bh[FN], al[SPLIT ? FM : 1], bl[SPLIT ? FN : 1];
#pragma unroll
        for (int i = 0; i < FM; ++i) {
            ah[i] = *(const short8*)&AsH[cur * ASZ + (wm + i * 16 + l15) * BK + quad * 8];
            if (SPLIT) al[i] = *(const short8*)&AsL[cur * ASZ + (wm + i * 16 + l15) * BK + quad * 8];
        }
#pragma unroll
        for (int j = 0; j < FN; ++j) {
            bh[j] = *(const short8*)&BsH[cur * BSZ + (wn + j * 16 + l15) * BK + quad * 8];
            if (SPLIT) bl[j] = *(const short8*)&BsL[cur * BSZ + (wn + j * 16 + l15) * BK + quad * 8];
        }
#pragma unroll
        for (int i = 0; i < FM; ++i)
#pragma unroll
            for (int j = 0; j < FN; ++j) {
                acc[i][j] = __builtin_amdgcn_mfma_f32_16x16x32_bf16(ah[i], bh[j], acc[i][j], 0, 0, 0);
                if (SPLIT) {
                    acc[i][j] = __builtin_amdgcn_mfma_f32_16x16x32_bf16(ah[i], bl[j], acc[i][j], 0, 0, 0);
                    acc[i][j] = __builtin_amdgcn_mfma_f32_16x16x32_bf16(al[i], bh[j], acc[i][j], 0, 0, 0);
                }
            }

        __syncthreads();
    }

#pragma unroll
    for (int i = 0; i < FM; ++i)
#pragma unroll
        for (int j = 0; j < FN; ++j) {
            const int m = m0 + wm + i * 16 + quad * 4;
            const int n = n0 + wn + j * 16 + l15;
#pragma unroll
            for (int r = 0; r < 4; ++r) {
                const float v = acc[i][j][r];
                const long idx = (long)(m + r) * ldc + n;
                if (OUTMODE == 0) {
                    Cf[idx] = v;
                } else if (OUTMODE == 1 || OUTMODE == 3) {
                    Ch[idx] = f2bf(v);
                } else {
                    const unsigned short hi = f2bf(v);
                    Ch[idx] = hi;
                    Cl[idx] = f2bf(v - bf2f(hi));
                }
            }
        }

    if (OUTMODE == 3) {
        const int slot = (blockIdx.z * gridDim.x + blockIdx.x) * 2 + (wn >> 6);
#pragma unroll
        for (int i = 0; i < FM; ++i)
#pragma unroll
            for (int r = 0; r < 4; ++r) {
                float s = 0.f, q = 0.f;
#pragma unroll
                for (int j = 0; j < FN; ++j) {
                    const float v = acc[i][j][r];
                    s += v; q += v * v;
                }
#pragma unroll
                for (int msk = 1; msk < 16; msk <<= 1) {
                    s += __shfl_xor(s, msk, 64);
                    q += __shfl_xor(q, msk, 64);
                }
                if (l15 == 0) {
                    const int row = m0 + wm + i * 16 + quad * 4 + r;
                    S1[(long)row * 256 + slot] = s;
                    S2[(long)row * 256 + slot] = q;
                }
            }
    }
}

// ---------------- fused scores+softmax+y v5.1 (R5 verified best) ----------------
// 512 blocks (b = id&7, kh = (id>>3)&1, qt = id>>4), 4 waves.
// S phase: 8 chunks of 32 c; chunk kc lives in column-half kc&1 of the
//   [128][64]+swz64 phi tile; per chunk {gload kc+2 | MFMA kc | write kc+1}
//   then ONE barrier. PV: square tiling (64q x 64p/wave), 4 chunks of 32 keys.
// LDS: FG 32,768B (aliased phi/G) + Pw 17,408B + Aly 256B = 50,432B.
#define PSTRP 136   // P LDS row stride (128 keys + 8 pad)

// swizzled short-offset into a [rows][64-short] tile: 16B slot ^= row&7
__device__ __forceinline__ int swz64(int row, int slot) {
    return (row << 6) + (((slot ^ row) & 7) << 3);
}

__global__ __launch_bounds__(256, 2) void fused_attn(
    const unsigned short* __restrict__ thphH,
    const unsigned short* __restrict__ thphL,
    const unsigned short* __restrict__ gbf,
    float* __restrict__ yp,       // [2][B][N][P] fp32 partials (self-normalized)
    float2* __restrict__ ml)      // [2][B*N] {m, l}
{
    const int N = 2048, P = 256, P2 = 512;
    const int id = blockIdx.x;
    const int b  = id & 7;            // XCD-locality heuristic
    const int kh = (id >> 3) & 1;     // key half
    const int qt = id >> 4;           // 0..31
    const int q0 = qt * 64;

    const unsigned short* thB = thphH + (long)b * N * P2;
    const unsigned short* tlB = thphL + (long)b * N * P2;
    const unsigned short* gB  = gbf   + (long)b * P * N;
    float*  ypB = yp + (long)kh * (8L * N * P) + (long)b * N * P;
    float2* mlB = ml + (long)kh * (8L * N) + (long)b * N;

    // phi hi/lo and G share the same LDS (disjoint phases / halves, fenced)
    __shared__ unsigned short FG[2 * 128 * 64];       // 16,384 shorts = 32,768 B
    unsigned short* Fh = FG;                          // [128][64] swizzled
    unsigned short* Fl = FG + 128 * 64;
    unsigned short* Gs = FG;                          // [256][64] swizzled
    __shared__ unsigned short Pw[4][16 * PSTRP];      // per-rowgroup P (shared)
    __shared__ float Aly[64];                         // per-row alpha / linv

    const int tid = threadIdx.x;
    const int wid = tid >> 6, lane = tid & 63;
    const int l15 = lane & 15, quad = lane >> 4;

    // theta fragments in registers: wave rows [q0+wid*16, +16), A m = l15
    short8 tHr[8], tLr[8];
    {
        const unsigned short* t1 = thB + (long)(q0 + wid * 16 + l15) * P2;
        const unsigned short* t2 = tlB + (long)(q0 + wid * 16 + l15) * P2;
#pragma unroll
        for (int kt = 0; kt < 8; ++kt) {
            tHr[kt] = *(const short8*)&t1[kt * 32 + quad * 8];
            tLr[kt] = *(const short8*)&t2[kt * 32 + quad * 8];
        }
    }

    float mrun[4], lrun[4];
#pragma unroll
    for (int r = 0; r < 4; ++r) { mrun[r] = -1e30f; lrun[r] = 0.f; }

    // oacc[g*4+pj]: rows g*16+quad*4+r, cols wid*64+pj*16+l15
    floatx4 oacc[16];
#pragma unroll
    for (int p = 0; p < 16; ++p) oacc[p] = (floatx4){0.f, 0.f, 0.f, 0.f};

    // staging: prow4 = tid>>2 (0..63), lslot = tid&3 (16B granule in 32-short half)
    const int prow4 = tid >> 2, lslot = tid & 3;
    short8 pfH[2][2], pfL[2][2];   // [set][s], set = chunk&1 (static under unroll)
    short8 pg[2][4];

    for (int mt = 0; mt < 8; ++mt) {
        const int m0 = kh * 1024 + mt * 128;

        // ---- S phase: 8 chunks of 32 c, half-column dbuf ----
        floatx4 sacc[8];
#pragma unroll
        for (int j = 0; j < 8; ++j) sacc[j] = (floatx4){0.f, 0.f, 0.f, 0.f};

        // prologue: chunk0 -> half0, prefetch chunk1.
#pragma unroll
        for (int s = 0; s < 2; ++s) {
            const long o = (long)(m0 + s * 64 + prow4) * P2 + P + 0 * 32 + lslot * 8;
            pfH[0][s] = *(const short8*)&thB[o];
            pfL[0][s] = *(const short8*)&tlB[o];
        }
#pragma unroll
        for (int s = 0; s < 2; ++s) {
            const int row = s * 64 + prow4;
            *(short8*)&Fh[swz64(row, lslot)] = pfH[0][s];
            *(short8*)&Fl[swz64(row, lslot)] = pfL[0][s];
        }
#pragma unroll
        for (int s = 0; s < 2; ++s) {
            const long o = (long)(m0 + s * 64 + prow4) * P2 + P + 1 * 32 + lslot * 8;
            pfH[1][s] = *(const short8*)&thB[o];
            pfL[1][s] = *(const short8*)&tlB[o];
        }
        __syncthreads();

#pragma unroll
        for (int kc = 0; kc < 8; ++kc) {
            if (kc < 6) {                        // prefetch chunk kc+2 into set kc&1
#pragma unroll
                for (int s = 0; s < 2; ++s) {
                    const long o = (long)(m0 + s * 64 + prow4) * P2 + P + (kc + 2) * 32 + lslot * 8;
                    pfH[kc & 1][s] = *(const short8*)&thB[o];
                    pfL[kc & 1][s] = *(const short8*)&tlB[o];
                }
            }
            const short8 aH = tHr[kc];
            const short8 aL = tLr[kc];
            const int half = (kc & 1) * 4;
            __builtin_amdgcn_s_setprio(1);
#pragma unroll
            for (int j = 0; j < 8; ++j) {
                const int ro = swz64(j * 16 + l15, half + quad);
                const short8 bh = *(const short8*)&Fh[ro];
                const short8 bl = *(const short8*)&Fl[ro];
                sacc[j] = __builtin_amdgcn_mfma_f32_16x16x32_bf16(aH, bh, sacc[j], 0, 0, 0);
                sacc[j] = __builtin_amdgcn_mfma_f32_16x16x32_bf16(aH, bl, sacc[j], 0, 0, 0);
                sacc[j] = __builtin_amdgcn_mfma_f32_16x16x32_bf16(aL, bh, sacc[j], 0, 0, 0);
            }
            __builtin_amdgcn_s_setprio(0);
            if (kc < 7) {                        // write chunk kc+1 into other half
                const int wh = ((kc + 1) & 1) * 4;
#pragma unroll
                for (int s = 0; s < 2; ++s) {
                    const int row = s * 64 + prow4;
                    *(short8*)&Fh[swz64(row, wh + lslot)] = pfH[(kc + 1) & 1][s];
                    *(short8*)&Fl[swz64(row, wh + lslot)] = pfL[(kc + 1) & 1][s];
                }
            }
            __syncthreads();
        }

        // ---- online softmax (registers only; rows = quad*4+r) ----
        float alpha[4];
#pragma unroll
        for (int r = 0; r < 4; ++r) {
            float v = sacc[0][r];
#pragma unroll
            for (int j = 1; j < 8; ++j) v = fmaxf(v, sacc[j][r]);
            v = fmaxf(v, __shfl_xor(v, 1, 64));
            v = fmaxf(v, __shfl_xor(v, 2, 64));
            v = fmaxf(v, __shfl_xor(v, 4, 64));
            v = fmaxf(v, __shfl_xor(v, 8, 64));
            const float mo = mrun[r];
            const float mn = fmaxf(mo, v);
            mrun[r] = mn;
            alpha[r] = __expf(mo - mn);
        }
        float lpart[4] = {0.f, 0.f, 0.f, 0.f};
#pragma unroll
        for (int j = 0; j < 8; ++j)
#pragma unroll
            for (int r = 0; r < 4; ++r) {
                const float p = __expf(sacc[j][r] - mrun[r]);
                Pw[wid][(quad * 4 + r) * PSTRP + j * 16 + l15] = f2bf(p);
                lpart[r] += p;
            }
#pragma unroll
        for (int r = 0; r < 4; ++r) {
            float s = lpart[r];
            s += __shfl_xor(s, 1, 64);
            s += __shfl_xor(s, 2, 64);
            s += __shfl_xor(s, 4, 64);
            s += __shfl_xor(s, 8, 64);
            lrun[r] = lrun[r] * alpha[r] + s;
        }
        if (l15 == 0) {                    // publish row alphas for PV rescale
#pragma unroll
            for (int r = 0; r < 4; ++r) Aly[wid * 16 + quad * 4 + r] = alpha[r];
        }

        // ---- PV phase: square tiling, 4 chunks of 32 keys, half dbuf ----
#pragma unroll
        for (int s = 0; s < 4; ++s)
            pg[0][s] = *(const short8*)&gB[(long)(s * 64 + prow4) * N + m0 + 0 * 32 + lslot * 8];
#pragma unroll
        for (int s = 0; s < 4; ++s)
            *(short8*)&Gs[swz64(s * 64 + prow4, lslot)] = pg[0][s];
#pragma unroll
        for (int s = 0; s < 4; ++s)
            pg[1][s] = *(const short8*)&gB[(long)(s * 64 + prow4) * N + m0 + 1 * 32 + lslot * 8];
        __syncthreads();   // G0 + Pw + Aly visible

        float alr[4][4];
#pragma unroll
        for (int g = 0; g < 4; ++g)
#pragma unroll
            for (int r = 0; r < 4; ++r) alr[g][r] = Aly[g * 16 + quad * 4 + r];
        int noresc = 1;
#pragma unroll
        for (int g = 0; g < 4; ++g)
#pragma unroll
            for (int r = 0; r < 4; ++r) noresc &= (alr[g][r] == 1.f);
        if (!__all(noresc)) {
#pragma unroll
            for (int g = 0; g < 4; ++g)
#pragma unroll
                for (int pj = 0; pj < 4; ++pj)
#pragma unroll
                    for (int r = 0; r < 4; ++r) oacc[g * 4 + pj][r] *= alr[g][r];
        }

#pragma unroll
        for (int mc = 0; mc < 4; ++mc) {
            if (mc < 2) {                        // prefetch chunk mc+2 into set mc&1
#pragma unroll
                for (int s = 0; s < 4; ++s)
                    pg[mc & 1][s] = *(const short8*)&gB[(long)(s * 64 + prow4) * N + m0 + (mc + 2) * 32 + lslot * 8];
            }
            const int half = (mc & 1) * 4;
            short8 af[4];
#pragma unroll
            for (int g = 0; g < 4; ++g)
                af[g] = *(const short8*)&Pw[g][l15 * PSTRP + mc * 32 + quad * 8];
            __builtin_amdgcn_s_setprio(1);
#pragma unroll
            for (int pj = 0; pj < 4; ++pj) {
                const short8 bg = *(const short8*)&Gs[swz64(wid * 64 + pj * 16 + l15, half + quad)];
#pragma unroll
                for (int g = 0; g < 4; ++g)
                    oacc[g * 4 + pj] = __builtin_amdgcn_mfma_f32_16x16x32_bf16(af[g], bg, oacc[g * 4 + pj], 0, 0, 0);
            }
            __builtin_amdgcn_s_setprio(0);
            if (mc < 3) {                        // write chunk mc+1 into other half
                const int wh = ((mc + 1) & 1) * 4;
#pragma unroll
                for (int s = 0; s < 4; ++s)
                    *(short8*)&Gs[swz64(s * 64 + prow4, wh + lslot)] = pg[(mc + 1) & 1][s];
                __syncthreads();
            }
        }
    }

    // ---- finalize: publish 1/l, scale, write fp32 partial + (m,l) ----
    if (l15 == 0) {
#pragma unroll
        for (int r = 0; r < 4; ++r) Aly[wid * 16 + quad * 4 + r] = 1.0f / lrun[r];
    }
    __syncthreads();
    float liv[4][4];
#pragma unroll
    for (int g = 0; g < 4; ++g)
#pragma unroll
        for (int r = 0; r < 4; ++r) liv[g][r] = Aly[g * 16 + quad * 4 + r];
#pragma unroll
    for (int g = 0; g < 4; ++g)
#pragma unroll
        for (int pj = 0; pj < 4; ++pj)
#pragma unroll
            for (int r = 0; r < 4; ++r) {
                const int row = q0 + g * 16 + quad * 4 + r;
                const int col = wid * 64 + pj * 16 + l15;
                ypB[(long)row * P + col] = oacc[g * 4 + pj][r] * liv[g][r];
            }
    if (l15 == 0) {
#pragma unroll
        for (int r = 0; r < 4; ++r) {
            const int row = q0 + wid * 16 + quad * 4 + r;
            mlB[row] = float2{mrun[r], lrun[r]};
        }
    }
}

// merge the two key-half partials: y = f1*y1 + f2*y2, f_i = l_i e^{m_i-m}/Z
__global__ __launch_bounds__(256) void attn_merge(
    const float* __restrict__ yp, const float2* __restrict__ ml,
    unsigned short* __restrict__ ybf)
{
    const long HALF = 8L * 2048 * 256;
    const long t = (long)blockIdx.x * 256 + threadIdx.x;
    const long row = t >> 5;
    const int  c0  = ((int)t & 31) * 8;
    const float2 a = ml[row];
    const float2 c = ml[8L * 2048 + row];
    const float mx = fmaxf(a.x, c.x);
    const float w1 = a.y * __expf(a.x - mx);
    const float w2 = c.y * __expf(c.x - mx);
    const float inv = 1.0f / (w1 + w2);
    const float f1 = w1 * inv, f2 = w2 * inv;
    const long base = row * 256 + c0;
    const float4 u0 = *(const float4*)&yp[base];
    const float4 u1 = *(const float4*)&yp[base + 4];
    const float4 v0 = *(const float4*)&yp[HALF + base];
    const float4 v1 = *(const float4*)&yp[HALF + base + 4];
    ushort4 o0, o1;
    o0.x = f2bf(f1 * u0.x + f2 * v0.x);
    o0.y = f2bf(f1 * u0.y + f2 * v0.y);
    o0.z = f2bf(f1 * u0.z + f2 * v0.z);
    o0.w = f2bf(f1 * u0.w + f2 * v0.w);
    o1.x = f2bf(f1 * u1.x + f2 * v1.x);
    o1.y = f2bf(f1 * u1.y + f2 * v1.y);
    o1.z = f2bf(f1 * u1.z + f2 * v1.z);
    o1.w = f2bf(f1 * u1.w + f2 * v1.w);
    *(ushort4*)&ybf[base] = o0;
    *(ushort4*)&ybf[base + 4] = o1;
}

// ---------------- BN finalize + apply ----------------
__global__ __launch_bounds__(256) void bn_finalize(
    const float* __restrict__ p1, const float* __restrict__ p2,
    float* __restrict__ mean, float* __restrict__ rstd, float cnt)
{
    const int c = blockIdx.x, t = threadIdx.x;
    __shared__ float rs[256], rq[256];
    rs[t] = p1[(long)c * 256 + t];
    rq[t] = p2[(long)c * 256 + t];
    __syncthreads();
    for (int st = 128; st > 0; st >>= 1) {
        if (t < st) { rs[t] += rs[t + st]; rq[t] += rq[t + st]; }
        __syncthreads();
    }
    if (t == 0) {
        const float m = rs[0] / cnt;
        mean[c] = m;
        rstd[c] = rsqrtf(rq[0] / cnt - m * m + 1e-5f);
    }
}

__global__ __launch_bounds__(256) void bn_apply_bf(
    const unsigned short* __restrict__ z, const float* __restrict__ x,
    const float* __restrict__ mean, const float* __restrict__ rstd,
    const float* __restrict__ gamma, const float* __restrict__ beta,
    float* __restrict__ out)
{
    const long i = ((long)blockIdx.x * 256 + threadIdx.x) * 8;
    const int c = (int)((i >> 11) & 511);    // (i / N) % C, N=2048, C=512
    const float mu = mean[c], rs = rstd[c], ga = gamma[c], be = beta[c];
    const ushort4 z0 = *(const ushort4*)&z[i];
    const ushort4 z1 = *(const ushort4*)&z[i + 4];
    const float4 x0 = *(const float4*)&x[i];
    const float4 x1 = *(const float4*)&x[i + 4];
    float4 o0, o1;
    o0.x = (bf2f(z0.x) - mu) * rs * ga + be + x0.x;
    o0.y = (bf2f(z0.y) - mu) * rs * ga + be + x0.y;
    o0.z = (bf2f(z0.z) - mu) * rs * ga + be + x0.z;
    o0.w = (bf2f(z0.w) - mu) * rs * ga + be + x0.w;
    o1.x = (bf2f(z1.x) - mu) * rs * ga + be + x1.x;
    o1.y = (bf2f(z1.y) - mu) * rs * ga + be + x1.y;
    o1.z = (bf2f(z1.z) - mu) * rs * ga + be + x1.z;
    o1.w = (bf2f(z1.w) - mu) * rs * ga + be + x1.w;
    *(float4*)&out[i] = o0;
    *(float4*)&out[i + 4] = o1;
}

extern "C" void kernel_launch(void* const* d_in, const int* in_sizes, int n_in,
                              void* d_out, int out_size, void* d_ws, size_t ws_size,
                              hipStream_t stream)
{
    const int B = 8, C = 512, N = 2048, P = 256;
    const float* x      = (const float*)d_in[0];
    const float* Wg     = (const float*)d_in[1];
    const float* Wtheta = (const float*)d_in[2];
    const float* Wphi   = (const float*)d_in[3];
    const float* Wz     = (const float*)d_in[4];
    const float* gamma  = (const float*)d_in[5];
    const float* beta   = (const float*)d_in[6];
    float* out = (float*)d_out;

    // ---- workspace layout (float units), same as round 9 ----
    float* ws = (float*)d_ws;
    const long NCle = (long)N * C;            // 1,048,576 per batch (= N*2P)
    const long NP   = (long)N * P;            // 524,288 per batch
    const long R0   = (long)B * NCle;         // 8.39M floats
    unsigned short* xtH   = (unsigned short*)ws;                // B*N*C
    unsigned short* xtL   = xtH + B * NCle;
    unsigned short* zbf   = (unsigned short*)ws;                // aliases xt (dead)
    unsigned short* thphH = (unsigned short*)(ws + R0);         // B*N*2P
    unsigned short* thphL = thphH + B * NCle;                   // B*N*2P
    unsigned short* gbf   = (unsigned short*)(ws + 2 * R0);     // B*P*N
    unsigned short* fbf   = gbf + B * NP;                       // attn partial region
    unsigned short* ybf   = fbf + (long)B * N * N;              // B*N*P
    unsigned short* W2H   = ybf + B * NP;                       // 2P*C
    unsigned short* W2L   = W2H + 2L * P * C;
    unsigned short* WgB   = W2L + 2L * P * C;                   // P*C
    unsigned short* WzB   = WgB + (long)P * C;
    // attn split-K partials in the dead fbf region; ml in dead xtL region.
    float*          yp    = (float*)fbf;                        // [2][B][N][P] fp32
    float2*         ml    = (float2*)(ws + 6L * 1024 * 1024);   // [2][B*N], in xtL
    // BN scratch aliases thph region (dead after fused_attn): [C][256] x2
    float*          bnp1  = ws + R0;
    float*          bnp2  = bnp1 + (long)C * 256;
    float*          mean  = bnp2 + (long)C * 256;
    float*          rstd  = mean + C;

    const long sX = (long)C * N;
    const int  P2 = 2 * P;

    // 1: transpose+split x -> xT hi/lo [B][N][C] (v2: 32x128 tiles)
    transpose_split<<<dim3(N / 128, C / 32, B), 256, 0, stream>>>(x, xtH, xtL, C, N);
    // 2: weight preps
    split_w2<<<(2 * P * C + 255) / 256, 256, 0, stream>>>(Wtheta, Wphi, W2H, W2L, P * C);
    cast_bf16<<<P * C / 1024, 256, 0, stream>>>(Wg, WgB);
    cast_bf16<<<P * C / 1024, 256, 0, stream>>>(Wz, WzB);

    // 3: thph [B][N][2P] = xT @ W2^T (split in/out); XYSWAP grid
    mfma_gemm<true, 2, 4, 4, true><<<dim3(N / 128, P2 / 128, B), 256, 0, stream>>>(
        xtH, xtL, W2H, W2L, thphH, thphL, C, C, C, P2, NCle, 0, NCle, nullptr, nullptr);
    // 4: g [B][P][N] = Wg @ xT^T (plain, bf16 out); 64x128, 512 blocks
    mfma_gemm<false, 1, 2, 4, false><<<dim3(N / 128, P / 64, B), 256, 0, stream>>>(
        WgB, WgB, xtH, xtH, gbf, gbf, C, C, C, N, 0, NCle, NP, nullptr, nullptr);

    // 5: fused scores+softmax+y, split-K x2 over keys (512 blocks, 2/CU) + merge
    fused_attn<<<dim3(512), 256, 0, stream>>>(thphH, thphL, gbf, yp, ml);
    attn_merge<<<dim3(2048), 256, 0, stream>>>(yp, ml, ybf);

    // 6: z [B][C][N] bf16 = Wz @ yT^T, BN partials (thph dead now)
    mfma_gemm<false, 3, 4, 4, false><<<dim3(N / 128, C / 128, B), 256, 0, stream>>>(
        WzB, WzB, ybf, ybf, zbf, zbf, P, P, P, N, 0, NP, sX, bnp1, bnp2);

    // 7: BN finalize + apply + residual
    bn_finalize<<<C, 256, 0, stream>>>(bnp1, bnp2, mean, rstd, (float)B * N);
    bn_apply_bf<<<(int)((B * sX) / 2048), 256, 0, stream>>>(zbf, x, mean, rstd, gamma, beta, out);
}